// Round 1
// baseline (1992.651 us; speedup 1.0000x reference)
//
#include <hip/hip_runtime.h>
#include <math.h>

#define HIDC 128
#define INC 100
#define OUTC 47

// ---------------- CSR build ----------------

__global__ __launch_bounds__(256) void k_deg(const int* __restrict__ dst, int* __restrict__ deg, int ne) {
    int e = blockIdx.x * 256 + threadIdx.x;
    if (e < ne) atomicAdd(&deg[dst[e]], 1);
}

__global__ __launch_bounds__(256) void k_scan1(const int* __restrict__ deg, int* __restrict__ local_s,
                                               int* __restrict__ bsum, int n) {
    __shared__ int s[256];
    int t = threadIdx.x;
    int i = blockIdx.x * 256 + t;
    int v = (i < n) ? deg[i] : 0;
    s[t] = v;
    __syncthreads();
    for (int off = 1; off < 256; off <<= 1) {
        int add = (t >= off) ? s[t - off] : 0;
        __syncthreads();
        s[t] += add;
        __syncthreads();
    }
    if (i < n) local_s[i] = s[t] - v;   // exclusive within block
    if (t == 255) bsum[blockIdx.x] = s[255];
}

__global__ __launch_bounds__(512) void k_scan2(int* __restrict__ bsum, int nb) {
    __shared__ int s[512];
    int t = threadIdx.x;
    int v = (t < nb) ? bsum[t] : 0;
    s[t] = v;
    __syncthreads();
    for (int off = 1; off < 512; off <<= 1) {
        int add = (t >= off) ? s[t - off] : 0;
        __syncthreads();
        s[t] += add;
        __syncthreads();
    }
    if (t < nb) bsum[t] = s[t] - v;     // exclusive block offsets
}

__global__ __launch_bounds__(256) void k_scan3(const int* __restrict__ local_s, const int* __restrict__ bsum,
                                               int* __restrict__ offs, int n, int ne) {
    int i = blockIdx.x * 256 + threadIdx.x;
    if (i < n) offs[i] = local_s[i] + bsum[blockIdx.x];
    if (i == 0) offs[n] = ne;
}

__global__ __launch_bounds__(256) void k_invdeg(const int* __restrict__ deg, float* __restrict__ invdeg, int n) {
    int i = blockIdx.x * 256 + threadIdx.x;
    if (i < n) invdeg[i] = 1.0f / (float)max(deg[i], 1);
}

__global__ __launch_bounds__(256) void k_fill(const int* __restrict__ src, const int* __restrict__ dst,
                                              const int* __restrict__ offs, int* __restrict__ curs,
                                              int* __restrict__ csr, int ne) {
    int e = blockIdx.x * 256 + threadIdx.x;
    if (e < ne) {
        int d = dst[e];
        int p = atomicAdd(&curs[d], 1);
        csr[offs[d] + p] = src[e];
    }
}

// ---------------- Aggregation (pull, mean) ----------------

__global__ __launch_bounds__(128) void k_agg(const float* __restrict__ h, const int* __restrict__ csr,
                                             const int* __restrict__ offs, const float* __restrict__ invdeg,
                                             float* __restrict__ agg) {
    int v = blockIdx.x;
    int j = threadIdx.x;
    int e0 = offs[v], e1 = offs[v + 1];
    float acc = 0.f;
    for (int e = e0; e < e1; ++e) {
        int sidx = csr[e];                       // wave-uniform
        acc += h[(size_t)sidx * HIDC + j];       // 512B coalesced row gather
    }
    agg[(size_t)v * HIDC + j] = acc * invdeg[v];
}

// ---------------- Input projection: inp = x@W + b ; h = relu(inp) ----------------

__global__ __launch_bounds__(256) void k_inproj(const float* __restrict__ x, const float* __restrict__ w,
                                                const float* __restrict__ b, float* __restrict__ inp,
                                                float* __restrict__ h, int n) {
    __shared__ float sX[16][INC];
    int t = threadIdx.x;
    int brow = blockIdx.x * 16;
    for (int idx = t; idx < 16 * INC; idx += 256) {
        int r = idx / INC, c = idx % INC;
        int row = brow + r;
        sX[r][c] = (row < n) ? x[(size_t)row * INC + c] : 0.f;
    }
    __syncthreads();
    int q = t >> 6, j = t & 63;   // rows q*4..q*4+3, cols j and j+64
    float acc0[4] = {0, 0, 0, 0}, acc1[4] = {0, 0, 0, 0};
    for (int k0 = 0; k0 < INC; k0 += 4) {
        float a_[4][4];
#pragma unroll
        for (int r = 0; r < 4; r++) {
            float4 t4 = *reinterpret_cast<const float4*>(&sX[q * 4 + r][k0]);
            a_[r][0] = t4.x; a_[r][1] = t4.y; a_[r][2] = t4.z; a_[r][3] = t4.w;
        }
#pragma unroll
        for (int kk = 0; kk < 4; kk++) {
            int k = k0 + kk;
            float w0 = w[k * HIDC + j];
            float w1 = w[k * HIDC + j + 64];
#pragma unroll
            for (int r = 0; r < 4; r++) {
                acc0[r] += a_[r][kk] * w0;
                acc1[r] += a_[r][kk] * w1;
            }
        }
    }
    float b0 = b[j], b1 = b[j + 64];
#pragma unroll
    for (int r = 0; r < 4; r++) {
        int row = brow + q * 4 + r;
        if (row < n) {
            float v0 = acc0[r] + b0, v1 = acc1[r] + b1;
            inp[(size_t)row * HIDC + j] = v0;
            inp[(size_t)row * HIDC + j + 64] = v1;
            h[(size_t)row * HIDC + j] = fmaxf(v0, 0.f);
            h[(size_t)row * HIDC + j + 64] = fmaxf(v1, 0.f);
        }
    }
}

// ---------------- Hidden SAGE layer: h = relu(agg@wl + bl + h@wr) + 0.2*inp (in-place) ----------------

__global__ __launch_bounds__(256) void k_gemm_hid(const float* __restrict__ agg, float* __restrict__ h,
                                                  const float* __restrict__ inp,
                                                  const float* __restrict__ wl, const float* __restrict__ bl,
                                                  const float* __restrict__ wr, int n) {
    __shared__ float sA[16][HIDC];
    __shared__ float sH[16][HIDC];
    int t = threadIdx.x;
    int brow = blockIdx.x * 16;
    for (int idx = t; idx < 16 * HIDC; idx += 256) {
        int r = idx >> 7, c = idx & 127;
        int row = brow + r;
        float a = 0.f, hv = 0.f;
        if (row < n) {
            a = agg[(size_t)row * HIDC + c];
            hv = h[(size_t)row * HIDC + c];
        }
        sA[r][c] = a;
        sH[r][c] = hv;
    }
    __syncthreads();
    int q = t >> 6, j = t & 63;
    float acc0[4] = {0, 0, 0, 0}, acc1[4] = {0, 0, 0, 0};
    for (int k0 = 0; k0 < HIDC; k0 += 4) {
        float a_[4][4], h_[4][4];
#pragma unroll
        for (int r = 0; r < 4; r++) {
            float4 t4 = *reinterpret_cast<const float4*>(&sA[q * 4 + r][k0]);
            a_[r][0] = t4.x; a_[r][1] = t4.y; a_[r][2] = t4.z; a_[r][3] = t4.w;
            float4 t5 = *reinterpret_cast<const float4*>(&sH[q * 4 + r][k0]);
            h_[r][0] = t5.x; h_[r][1] = t5.y; h_[r][2] = t5.z; h_[r][3] = t5.w;
        }
#pragma unroll
        for (int kk = 0; kk < 4; kk++) {
            int k = k0 + kk;
            float wl0 = wl[k * HIDC + j];
            float wl1 = wl[k * HIDC + j + 64];
            float wr0 = wr[k * HIDC + j];
            float wr1 = wr[k * HIDC + j + 64];
#pragma unroll
            for (int r = 0; r < 4; r++) {
                acc0[r] += a_[r][kk] * wl0 + h_[r][kk] * wr0;
                acc1[r] += a_[r][kk] * wl1 + h_[r][kk] * wr1;
            }
        }
    }
    float b0 = bl[j], b1 = bl[j + 64];
#pragma unroll
    for (int r = 0; r < 4; r++) {
        int row = brow + q * 4 + r;
        if (row < n) {
            float v0 = fmaxf(acc0[r] + b0, 0.f) + 0.2f * inp[(size_t)row * HIDC + j];
            float v1 = fmaxf(acc1[r] + b1, 0.f) + 0.2f * inp[(size_t)row * HIDC + j + 64];
            h[(size_t)row * HIDC + j] = v0;
            h[(size_t)row * HIDC + j + 64] = v1;
        }
    }
}

// ---------------- Output layer + log_softmax (wave per row) ----------------

__global__ __launch_bounds__(256) void k_out(const float* __restrict__ agg, const float* __restrict__ h,
                                             const float* __restrict__ wl, const float* __restrict__ bl,
                                             const float* __restrict__ wr, float* __restrict__ out, int n) {
    int wave = threadIdx.x >> 6, lane = threadIdx.x & 63;
    int row = blockIdx.x * 4 + wave;
    if (row >= n) return;
    bool act = lane < OUTC;
    int j = act ? lane : (OUTC - 1);
    const float* ar = agg + (size_t)row * HIDC;
    const float* hr = h + (size_t)row * HIDC;
    float acc = 0.f;
    for (int k = 0; k < HIDC; k++) {
        float a = ar[k];    // wave-uniform
        float hh = hr[k];
        acc += a * wl[k * OUTC + j] + hh * wr[k * OUTC + j];
    }
    float val = acc + bl[j];
    float m = act ? val : -INFINITY;
#pragma unroll
    for (int off = 32; off; off >>= 1) m = fmaxf(m, __shfl_xor(m, off));
    float ex = act ? __expf(val - m) : 0.f;
    float s = ex;
#pragma unroll
    for (int off = 32; off; off >>= 1) s += __shfl_xor(s, off);
    if (act) out[(size_t)row * OUTC + lane] = val - m - logf(s);
}

// ---------------- Launch ----------------

extern "C" void kernel_launch(void* const* d_in, const int* in_sizes, int n_in,
                              void* d_out, int out_size, void* d_ws, size_t ws_size,
                              hipStream_t stream) {
    const float* x        = (const float*)d_in[0];
    const int*   ei       = (const int*)d_in[1];
    const float* inproj_w = (const float*)d_in[2];
    const float* inproj_b = (const float*)d_in[3];
    const float* wl_h     = (const float*)d_in[4];
    const float* bl_h     = (const float*)d_in[5];
    const float* wr_h     = (const float*)d_in[6];
    const float* wl_out   = (const float*)d_in[7];
    const float* bl_out   = (const float*)d_in[8];
    const float* wr_out   = (const float*)d_in[9];
    float* out = (float*)d_out;

    int n  = in_sizes[0] / INC;   // 100000
    int ne = in_sizes[1] / 2;     // 1600000
    const int* src = ei;
    const int* dst = ei + ne;

    char* ws = (char*)d_ws;
    size_t off = 0;
    auto alloc = [&](size_t bytes) -> void* {
        void* p = ws + off;
        off = (off + bytes + 255) & ~(size_t)255;
        return p;
    };
    float* inp    = (float*)alloc((size_t)n * HIDC * 4);
    float* h      = (float*)alloc((size_t)n * HIDC * 4);
    float* agg    = (float*)alloc((size_t)n * HIDC * 4);
    int*   deg    = (int*)alloc((size_t)n * 4);
    float* invdeg = (float*)alloc((size_t)n * 4);
    int*   local_s= (int*)alloc((size_t)n * 4);
    int*   bsum   = (int*)alloc(512 * 4);
    int*   offs   = (int*)alloc((size_t)(n + 1) * 4);
    int*   curs   = (int*)alloc((size_t)n * 4);
    int*   csr    = (int*)alloc((size_t)ne * 4);

    hipMemsetAsync(deg, 0, (size_t)n * 4, stream);
    hipMemsetAsync(curs, 0, (size_t)n * 4, stream);

    int nbE = (ne + 255) / 256;
    int nbN = (n + 255) / 256;    // 391 <= 512, required by k_scan2
    k_deg<<<nbE, 256, 0, stream>>>(dst, deg, ne);
    k_scan1<<<nbN, 256, 0, stream>>>(deg, local_s, bsum, n);
    k_scan2<<<1, 512, 0, stream>>>(bsum, nbN);
    k_scan3<<<nbN, 256, 0, stream>>>(local_s, bsum, offs, n, ne);
    k_invdeg<<<nbN, 256, 0, stream>>>(deg, invdeg, n);
    k_fill<<<nbE, 256, 0, stream>>>(src, dst, offs, curs, csr, ne);

    int nbR = (n + 15) / 16;
    k_inproj<<<nbR, 256, 0, stream>>>(x, inproj_w, inproj_b, inp, h, n);
    for (int l = 0; l < 3; ++l) {
        k_agg<<<n, 128, 0, stream>>>(h, csr, offs, invdeg, agg);
        k_gemm_hid<<<nbR, 256, 0, stream>>>(agg, h, inp,
                                            wl_h + (size_t)l * HIDC * HIDC,
                                            bl_h + (size_t)l * HIDC,
                                            wr_h + (size_t)l * HIDC * HIDC, n);
    }
    k_agg<<<n, 128, 0, stream>>>(h, csr, offs, invdeg, agg);
    k_out<<<(n + 3) / 4, 256, 0, stream>>>(agg, h, wl_out, bl_out, wr_out, out, n);
}

// Round 2
// 1550.266 us; speedup vs baseline: 1.2854x; 1.2854x over previous
//
#include <hip/hip_runtime.h>
#include <math.h>

#define HIDC 128
#define INC 100
#define OUTC 47

// ---------------- CSR build ----------------

__global__ __launch_bounds__(256) void k_deg(const int* __restrict__ dst, int* __restrict__ deg, int ne) {
    int e = blockIdx.x * 256 + threadIdx.x;
    if (e < ne) atomicAdd(&deg[dst[e]], 1);
}

__global__ __launch_bounds__(256) void k_scan1(const int* __restrict__ deg, int* __restrict__ local_s,
                                               int* __restrict__ bsum, int n) {
    __shared__ int s[256];
    int t = threadIdx.x;
    int i = blockIdx.x * 256 + t;
    int v = (i < n) ? deg[i] : 0;
    s[t] = v;
    __syncthreads();
    for (int off = 1; off < 256; off <<= 1) {
        int add = (t >= off) ? s[t - off] : 0;
        __syncthreads();
        s[t] += add;
        __syncthreads();
    }
    if (i < n) local_s[i] = s[t] - v;   // exclusive within block
    if (t == 255) bsum[blockIdx.x] = s[255];
}

__global__ __launch_bounds__(512) void k_scan2(int* __restrict__ bsum, int nb) {
    __shared__ int s[512];
    int t = threadIdx.x;
    int v = (t < nb) ? bsum[t] : 0;
    s[t] = v;
    __syncthreads();
    for (int off = 1; off < 512; off <<= 1) {
        int add = (t >= off) ? s[t - off] : 0;
        __syncthreads();
        s[t] += add;
        __syncthreads();
    }
    if (t < nb) bsum[t] = s[t] - v;     // exclusive block offsets
}

__global__ __launch_bounds__(256) void k_scan3(const int* __restrict__ local_s, const int* __restrict__ bsum,
                                               int* __restrict__ offs, int n, int ne) {
    int i = blockIdx.x * 256 + threadIdx.x;
    if (i < n) offs[i] = local_s[i] + bsum[blockIdx.x];
    if (i == 0) offs[n] = ne;
}

__global__ __launch_bounds__(256) void k_invdeg(const int* __restrict__ deg, float* __restrict__ invdeg, int n) {
    int i = blockIdx.x * 256 + threadIdx.x;
    if (i < n) invdeg[i] = 1.0f / (float)max(deg[i], 1);
}

__global__ __launch_bounds__(256) void k_fill(const int* __restrict__ src, const int* __restrict__ dst,
                                              const int* __restrict__ offs, int* __restrict__ curs,
                                              int* __restrict__ csr, int ne) {
    int e = blockIdx.x * 256 + threadIdx.x;
    if (e < ne) {
        int d = dst[e];
        int p = atomicAdd(&curs[d], 1);
        csr[offs[d] + p] = src[e];
    }
}

// ---------------- Aggregation (pull, mean): wave per node, float4, 2 edges/iter ----------------

__global__ __launch_bounds__(256) void k_agg(const float* __restrict__ h, const int* __restrict__ csr,
                                             const int* __restrict__ offs, const float* __restrict__ invdeg,
                                             float* __restrict__ agg, int n) {
    int wv = threadIdx.x >> 6, lane = threadIdx.x & 63;
    int v = blockIdx.x * 4 + wv;
    if (v >= n) return;
    int e0 = offs[v], e1 = offs[v + 1];
    int half = lane >> 5;     // lanes 0-31: even edges; 32-63: odd edges
    int c4 = lane & 31;       // float4 column index (32 x 16B = 512B row)
    float4 acc = {0.f, 0.f, 0.f, 0.f};
    for (int e = e0 + half; e < e1; e += 2) {
        int sidx = csr[e];
        float4 t = reinterpret_cast<const float4*>(h + (size_t)sidx * HIDC)[c4];
        acc.x += t.x; acc.y += t.y; acc.z += t.z; acc.w += t.w;
    }
    acc.x += __shfl_xor(acc.x, 32);
    acc.y += __shfl_xor(acc.y, 32);
    acc.z += __shfl_xor(acc.z, 32);
    acc.w += __shfl_xor(acc.w, 32);
    if (half == 0) {
        float s = invdeg[v];
        acc.x *= s; acc.y *= s; acc.z *= s; acc.w *= s;
        reinterpret_cast<float4*>(agg + (size_t)v * HIDC)[c4] = acc;
    }
}

// ---------------- Input projection: inp = x@W + b ; h = relu(inp) ----------------

__global__ __launch_bounds__(256) void k_inproj(const float* __restrict__ x, const float* __restrict__ w,
                                                const float* __restrict__ b, float* __restrict__ inp,
                                                float* __restrict__ h, int n) {
    __shared__ float sX[16][INC];
    int t = threadIdx.x;
    int brow = blockIdx.x * 16;
    for (int idx = t; idx < 16 * INC; idx += 256) {
        int r = idx / INC, c = idx % INC;
        int row = brow + r;
        sX[r][c] = (row < n) ? x[(size_t)row * INC + c] : 0.f;
    }
    __syncthreads();
    int q = t >> 6, j = t & 63;   // rows q*4..q*4+3, cols j and j+64
    float acc0[4] = {0, 0, 0, 0}, acc1[4] = {0, 0, 0, 0};
    for (int k0 = 0; k0 < INC; k0 += 4) {
        float a_[4][4];
#pragma unroll
        for (int r = 0; r < 4; r++) {
            float4 t4 = *reinterpret_cast<const float4*>(&sX[q * 4 + r][k0]);
            a_[r][0] = t4.x; a_[r][1] = t4.y; a_[r][2] = t4.z; a_[r][3] = t4.w;
        }
#pragma unroll
        for (int kk = 0; kk < 4; kk++) {
            int k = k0 + kk;
            float w0 = w[k * HIDC + j];
            float w1 = w[k * HIDC + j + 64];
#pragma unroll
            for (int r = 0; r < 4; r++) {
                acc0[r] += a_[r][kk] * w0;
                acc1[r] += a_[r][kk] * w1;
            }
        }
    }
    float b0 = b[j], b1 = b[j + 64];
#pragma unroll
    for (int r = 0; r < 4; r++) {
        int row = brow + q * 4 + r;
        if (row < n) {
            float v0 = acc0[r] + b0, v1 = acc1[r] + b1;
            inp[(size_t)row * HIDC + j] = v0;
            inp[(size_t)row * HIDC + j + 64] = v1;
            h[(size_t)row * HIDC + j] = fmaxf(v0, 0.f);
            h[(size_t)row * HIDC + j + 64] = fmaxf(v1, 0.f);
        }
    }
}

// ---------------- Hidden SAGE layer: h = relu(agg@wl + bl + h@wr) + 0.2*inp (in-place) ----------------

__global__ __launch_bounds__(256) void k_gemm_hid(const float* __restrict__ agg, float* __restrict__ h,
                                                  const float* __restrict__ inp,
                                                  const float* __restrict__ wl, const float* __restrict__ bl,
                                                  const float* __restrict__ wr, int n) {
    __shared__ float sA[16][HIDC];
    __shared__ float sH[16][HIDC];
    int t = threadIdx.x;
    int brow = blockIdx.x * 16;
    for (int idx = t; idx < 16 * HIDC; idx += 256) {
        int r = idx >> 7, c = idx & 127;
        int row = brow + r;
        float a = 0.f, hv = 0.f;
        if (row < n) {
            a = agg[(size_t)row * HIDC + c];
            hv = h[(size_t)row * HIDC + c];
        }
        sA[r][c] = a;
        sH[r][c] = hv;
    }
    __syncthreads();
    int q = t >> 6, j = t & 63;
    float acc0[4] = {0, 0, 0, 0}, acc1[4] = {0, 0, 0, 0};
    for (int k0 = 0; k0 < HIDC; k0 += 4) {
        float a_[4][4], h_[4][4];
#pragma unroll
        for (int r = 0; r < 4; r++) {
            float4 t4 = *reinterpret_cast<const float4*>(&sA[q * 4 + r][k0]);
            a_[r][0] = t4.x; a_[r][1] = t4.y; a_[r][2] = t4.z; a_[r][3] = t4.w;
            float4 t5 = *reinterpret_cast<const float4*>(&sH[q * 4 + r][k0]);
            h_[r][0] = t5.x; h_[r][1] = t5.y; h_[r][2] = t5.z; h_[r][3] = t5.w;
        }
#pragma unroll
        for (int kk = 0; kk < 4; kk++) {
            int k = k0 + kk;
            float wl0 = wl[k * HIDC + j];
            float wl1 = wl[k * HIDC + j + 64];
            float wr0 = wr[k * HIDC + j];
            float wr1 = wr[k * HIDC + j + 64];
#pragma unroll
            for (int r = 0; r < 4; r++) {
                acc0[r] += a_[r][kk] * wl0 + h_[r][kk] * wr0;
                acc1[r] += a_[r][kk] * wl1 + h_[r][kk] * wr1;
            }
        }
    }
    float b0 = bl[j], b1 = bl[j + 64];
#pragma unroll
    for (int r = 0; r < 4; r++) {
        int row = brow + q * 4 + r;
        if (row < n) {
            float v0 = fmaxf(acc0[r] + b0, 0.f) + 0.2f * inp[(size_t)row * HIDC + j];
            float v1 = fmaxf(acc1[r] + b1, 0.f) + 0.2f * inp[(size_t)row * HIDC + j + 64];
            h[(size_t)row * HIDC + j] = v0;
            h[(size_t)row * HIDC + j + 64] = v1;
        }
    }
}

// ---------------- Output layer (tiled GEMM) + log_softmax ----------------

__global__ __launch_bounds__(256) void k_out(const float* __restrict__ agg, const float* __restrict__ h,
                                             const float* __restrict__ wl, const float* __restrict__ bl,
                                             const float* __restrict__ wr, float* __restrict__ out, int n) {
    __shared__ float sA[16][HIDC];
    __shared__ float sH[16][HIDC];
    __shared__ float sO[16][48];
    int t = threadIdx.x;
    int brow = blockIdx.x * 16;
    for (int idx = t; idx < 16 * HIDC; idx += 256) {
        int r = idx >> 7, c = idx & 127;
        int row = brow + r;
        float a = 0.f, hv = 0.f;
        if (row < n) {
            a = agg[(size_t)row * HIDC + c];
            hv = h[(size_t)row * HIDC + c];
        }
        sA[r][c] = a;
        sH[r][c] = hv;
    }
    __syncthreads();
    int q = t >> 6, j = t & 63;   // rows q*4..q*4+3, col j (j<47 active)
    if (j < OUTC) {
        float acc[4] = {0, 0, 0, 0};
        for (int k0 = 0; k0 < HIDC; k0 += 4) {
            float a_[4][4], h_[4][4];
#pragma unroll
            for (int r = 0; r < 4; r++) {
                float4 t4 = *reinterpret_cast<const float4*>(&sA[q * 4 + r][k0]);
                a_[r][0] = t4.x; a_[r][1] = t4.y; a_[r][2] = t4.z; a_[r][3] = t4.w;
                float4 t5 = *reinterpret_cast<const float4*>(&sH[q * 4 + r][k0]);
                h_[r][0] = t5.x; h_[r][1] = t5.y; h_[r][2] = t5.z; h_[r][3] = t5.w;
            }
#pragma unroll
            for (int kk = 0; kk < 4; kk++) {
                int k = k0 + kk;
                float wlv = wl[k * OUTC + j];
                float wrv = wr[k * OUTC + j];
#pragma unroll
                for (int r = 0; r < 4; r++) acc[r] += a_[r][kk] * wlv + h_[r][kk] * wrv;
            }
        }
        float bv = bl[j];
#pragma unroll
        for (int r = 0; r < 4; r++) sO[q * 4 + r][j] = acc[r] + bv;
    }
    __syncthreads();
    // log_softmax: wave q handles rows q*4..q*4+3
    int lane = t & 63;
#pragma unroll
    for (int r = 0; r < 4; r++) {
        int row = brow + q * 4 + r;
        bool act = (lane < OUTC) && (row < n);
        float val = act ? sO[q * 4 + r][lane] : -INFINITY;
        float m = val;
#pragma unroll
        for (int off = 32; off; off >>= 1) m = fmaxf(m, __shfl_xor(m, off));
        float ex = act ? __expf(val - m) : 0.f;
        float s = ex;
#pragma unroll
        for (int off = 32; off; off >>= 1) s += __shfl_xor(s, off);
        if (act) out[(size_t)row * OUTC + lane] = val - m - logf(s);
    }
}

// ---------------- Launch ----------------

extern "C" void kernel_launch(void* const* d_in, const int* in_sizes, int n_in,
                              void* d_out, int out_size, void* d_ws, size_t ws_size,
                              hipStream_t stream) {
    const float* x        = (const float*)d_in[0];
    const int*   ei       = (const int*)d_in[1];
    const float* inproj_w = (const float*)d_in[2];
    const float* inproj_b = (const float*)d_in[3];
    const float* wl_h     = (const float*)d_in[4];
    const float* bl_h     = (const float*)d_in[5];
    const float* wr_h     = (const float*)d_in[6];
    const float* wl_out   = (const float*)d_in[7];
    const float* bl_out   = (const float*)d_in[8];
    const float* wr_out   = (const float*)d_in[9];
    float* out = (float*)d_out;

    int n  = in_sizes[0] / INC;   // 100000
    int ne = in_sizes[1] / 2;     // 1600000
    const int* src = ei;
    const int* dst = ei + ne;

    char* ws = (char*)d_ws;
    size_t off = 0;
    auto alloc = [&](size_t bytes) -> void* {
        void* p = ws + off;
        off = (off + bytes + 255) & ~(size_t)255;
        return p;
    };
    float* inp    = (float*)alloc((size_t)n * HIDC * 4);
    float* h      = (float*)alloc((size_t)n * HIDC * 4);
    float* agg    = (float*)alloc((size_t)n * HIDC * 4);
    int*   deg    = (int*)alloc((size_t)n * 4);
    float* invdeg = (float*)alloc((size_t)n * 4);
    int*   local_s= (int*)alloc((size_t)n * 4);
    int*   bsum   = (int*)alloc(512 * 4);
    int*   offs   = (int*)alloc((size_t)(n + 1) * 4);
    int*   curs   = (int*)alloc((size_t)n * 4);
    int*   csr    = (int*)alloc((size_t)ne * 4);

    hipMemsetAsync(deg, 0, (size_t)n * 4, stream);
    hipMemsetAsync(curs, 0, (size_t)n * 4, stream);

    int nbE = (ne + 255) / 256;
    int nbN = (n + 255) / 256;    // 391 <= 512, required by k_scan2
    k_deg<<<nbE, 256, 0, stream>>>(dst, deg, ne);
    k_scan1<<<nbN, 256, 0, stream>>>(deg, local_s, bsum, n);
    k_scan2<<<1, 512, 0, stream>>>(bsum, nbN);
    k_scan3<<<nbN, 256, 0, stream>>>(local_s, bsum, offs, n, ne);
    k_invdeg<<<nbN, 256, 0, stream>>>(deg, invdeg, n);
    k_fill<<<nbE, 256, 0, stream>>>(src, dst, offs, curs, csr, ne);

    int nbR = (n + 15) / 16;
    int nbA = (n + 3) / 4;
    k_inproj<<<nbR, 256, 0, stream>>>(x, inproj_w, inproj_b, inp, h, n);
    for (int l = 0; l < 3; ++l) {
        k_agg<<<nbA, 256, 0, stream>>>(h, csr, offs, invdeg, agg, n);
        k_gemm_hid<<<nbR, 256, 0, stream>>>(agg, h, inp,
                                            wl_h + (size_t)l * HIDC * HIDC,
                                            bl_h + (size_t)l * HIDC,
                                            wr_h + (size_t)l * HIDC * HIDC, n);
    }
    k_agg<<<nbA, 256, 0, stream>>>(h, csr, offs, invdeg, agg, n);
    k_out<<<nbR, 256, 0, stream>>>(agg, h, wl_out, bl_out, wr_out, out, n);
}

// Round 3
// 1419.489 us; speedup vs baseline: 1.4038x; 1.0921x over previous
//
#include <hip/hip_runtime.h>
#include <math.h>

#define HIDC 128
#define INC 100
#define OUTC 47

// ---------------- CSR build ----------------

__global__ __launch_bounds__(256) void k_deg(const int* __restrict__ dst, int* __restrict__ deg, int ne) {
    int e = blockIdx.x * 256 + threadIdx.x;
    if (e < ne) atomicAdd(&deg[dst[e]], 1);
}

__global__ __launch_bounds__(256) void k_scan1(const int* __restrict__ deg, int* __restrict__ local_s,
                                               int* __restrict__ bsum, int n) {
    __shared__ int s[256];
    int t = threadIdx.x;
    int i = blockIdx.x * 256 + t;
    int v = (i < n) ? deg[i] : 0;
    s[t] = v;
    __syncthreads();
    for (int off = 1; off < 256; off <<= 1) {
        int add = (t >= off) ? s[t - off] : 0;
        __syncthreads();
        s[t] += add;
        __syncthreads();
    }
    if (i < n) local_s[i] = s[t] - v;   // exclusive within block
    if (t == 255) bsum[blockIdx.x] = s[255];
}

__global__ __launch_bounds__(512) void k_scan2(int* __restrict__ bsum, int nb) {
    __shared__ int s[512];
    int t = threadIdx.x;
    int v = (t < nb) ? bsum[t] : 0;
    s[t] = v;
    __syncthreads();
    for (int off = 1; off < 512; off <<= 1) {
        int add = (t >= off) ? s[t - off] : 0;
        __syncthreads();
        s[t] += add;
        __syncthreads();
    }
    if (t < nb) bsum[t] = s[t] - v;     // exclusive block offsets
}

__global__ __launch_bounds__(256) void k_scan3(const int* __restrict__ local_s, const int* __restrict__ bsum,
                                               int* __restrict__ offs, int n, int ne) {
    int i = blockIdx.x * 256 + threadIdx.x;
    if (i < n) offs[i] = local_s[i] + bsum[blockIdx.x];
    if (i == 0) offs[n] = ne;
}

__global__ __launch_bounds__(256) void k_invdeg(const int* __restrict__ deg, float* __restrict__ invdeg, int n) {
    int i = blockIdx.x * 256 + threadIdx.x;
    if (i < n) invdeg[i] = 1.0f / (float)max(deg[i], 1);
}

__global__ __launch_bounds__(256) void k_fill(const int* __restrict__ src, const int* __restrict__ dst,
                                              const int* __restrict__ offs, int* __restrict__ curs,
                                              int* __restrict__ csr, int ne) {
    int e = blockIdx.x * 256 + threadIdx.x;
    if (e < ne) {
        int d = dst[e];
        int p = atomicAdd(&curs[d], 1);
        csr[offs[d] + p] = src[e];
    }
}

// ---------------- Aggregation (pull, mean): wave per node, float4, 2 edges/iter ----------------

__global__ __launch_bounds__(256) void k_agg(const float* __restrict__ h, const int* __restrict__ csr,
                                             const int* __restrict__ offs, const float* __restrict__ invdeg,
                                             float* __restrict__ agg, int n) {
    int wv = threadIdx.x >> 6, lane = threadIdx.x & 63;
    int v = blockIdx.x * 4 + wv;
    if (v >= n) return;
    int e0 = offs[v], e1 = offs[v + 1];
    int half = lane >> 5;     // lanes 0-31: even edges; 32-63: odd edges
    int c4 = lane & 31;       // float4 column index (32 x 16B = 512B row)
    float4 acc = {0.f, 0.f, 0.f, 0.f};
    for (int e = e0 + half; e < e1; e += 2) {
        int sidx = csr[e];
        float4 t = reinterpret_cast<const float4*>(h + (size_t)sidx * HIDC)[c4];
        acc.x += t.x; acc.y += t.y; acc.z += t.z; acc.w += t.w;
    }
    acc.x += __shfl_xor(acc.x, 32);
    acc.y += __shfl_xor(acc.y, 32);
    acc.z += __shfl_xor(acc.z, 32);
    acc.w += __shfl_xor(acc.w, 32);
    if (half == 0) {
        float s = invdeg[v];
        acc.x *= s; acc.y *= s; acc.z *= s; acc.w *= s;
        reinterpret_cast<float4*>(agg + (size_t)v * HIDC)[c4] = acc;
    }
}

// ---------------- Input projection: inp = x@W + b ; h = relu(inp) ----------------

__global__ __launch_bounds__(256) void k_inproj(const float* __restrict__ x, const float* __restrict__ w,
                                                const float* __restrict__ b, float* __restrict__ inp,
                                                float* __restrict__ h, int n) {
    __shared__ float sX[16][INC];
    int t = threadIdx.x;
    int brow = blockIdx.x * 16;
    for (int idx = t; idx < 16 * INC; idx += 256) {
        int r = idx / INC, c = idx % INC;
        int row = brow + r;
        sX[r][c] = (row < n) ? x[(size_t)row * INC + c] : 0.f;
    }
    __syncthreads();
    int q = t >> 6, j = t & 63;   // rows q*4..q*4+3, cols j and j+64
    float acc0[4] = {0, 0, 0, 0}, acc1[4] = {0, 0, 0, 0};
#pragma unroll 2
    for (int k0 = 0; k0 < INC; k0 += 4) {
        float a_[4][4];
#pragma unroll
        for (int r = 0; r < 4; r++) {
            float4 t4 = *reinterpret_cast<const float4*>(&sX[q * 4 + r][k0]);
            a_[r][0] = t4.x; a_[r][1] = t4.y; a_[r][2] = t4.z; a_[r][3] = t4.w;
        }
#pragma unroll
        for (int kk = 0; kk < 4; kk++) {
            int k = k0 + kk;
            float w0 = w[k * HIDC + j];
            float w1 = w[k * HIDC + j + 64];
#pragma unroll
            for (int r = 0; r < 4; r++) {
                acc0[r] += a_[r][kk] * w0;
                acc1[r] += a_[r][kk] * w1;
            }
        }
    }
    float b0 = b[j], b1 = b[j + 64];
#pragma unroll
    for (int r = 0; r < 4; r++) {
        int row = brow + q * 4 + r;
        if (row < n) {
            float v0 = acc0[r] + b0, v1 = acc1[r] + b1;
            inp[(size_t)row * HIDC + j] = v0;
            inp[(size_t)row * HIDC + j + 64] = v1;
            h[(size_t)row * HIDC + j] = fmaxf(v0, 0.f);
            h[(size_t)row * HIDC + j + 64] = fmaxf(v1, 0.f);
        }
    }
}

// ---------------- Hidden SAGE layer: h = relu(agg@wl + bl + h@wr) + 0.2*inp (in-place) ----------------

__global__ __launch_bounds__(256) void k_gemm_hid(const float* __restrict__ agg, float* __restrict__ h,
                                                  const float* __restrict__ inp,
                                                  const float* __restrict__ wl, const float* __restrict__ bl,
                                                  const float* __restrict__ wr, int n) {
    __shared__ float sA[16][HIDC];
    __shared__ float sH[16][HIDC];
    int t = threadIdx.x;
    int brow = blockIdx.x * 16;
    for (int idx = t; idx < 16 * HIDC; idx += 256) {
        int r = idx >> 7, c = idx & 127;
        int row = brow + r;
        float a = 0.f, hv = 0.f;
        if (row < n) {
            a = agg[(size_t)row * HIDC + c];
            hv = h[(size_t)row * HIDC + c];
        }
        sA[r][c] = a;
        sH[r][c] = hv;
    }
    __syncthreads();
    int q = t >> 6, j = t & 63;
    float acc0[4] = {0, 0, 0, 0}, acc1[4] = {0, 0, 0, 0};
#pragma unroll 2
    for (int k0 = 0; k0 < HIDC; k0 += 4) {
        float a_[4][4], h_[4][4];
#pragma unroll
        for (int r = 0; r < 4; r++) {
            float4 t4 = *reinterpret_cast<const float4*>(&sA[q * 4 + r][k0]);
            a_[r][0] = t4.x; a_[r][1] = t4.y; a_[r][2] = t4.z; a_[r][3] = t4.w;
            float4 t5 = *reinterpret_cast<const float4*>(&sH[q * 4 + r][k0]);
            h_[r][0] = t5.x; h_[r][1] = t5.y; h_[r][2] = t5.z; h_[r][3] = t5.w;
        }
#pragma unroll
        for (int kk = 0; kk < 4; kk++) {
            int k = k0 + kk;
            float wl0 = wl[k * HIDC + j];
            float wl1 = wl[k * HIDC + j + 64];
            float wr0 = wr[k * HIDC + j];
            float wr1 = wr[k * HIDC + j + 64];
#pragma unroll
            for (int r = 0; r < 4; r++) {
                acc0[r] += a_[r][kk] * wl0 + h_[r][kk] * wr0;
                acc1[r] += a_[r][kk] * wl1 + h_[r][kk] * wr1;
            }
        }
    }
    float b0 = bl[j], b1 = bl[j + 64];
#pragma unroll
    for (int r = 0; r < 4; r++) {
        int row = brow + q * 4 + r;
        if (row < n) {
            float v0 = fmaxf(acc0[r] + b0, 0.f) + 0.2f * inp[(size_t)row * HIDC + j];
            float v1 = fmaxf(acc1[r] + b1, 0.f) + 0.2f * inp[(size_t)row * HIDC + j + 64];
            h[(size_t)row * HIDC + j] = v0;
            h[(size_t)row * HIDC + j + 64] = v1;
        }
    }
}

// ---------------- Output layer (tiled GEMM) + log_softmax ----------------

__global__ __launch_bounds__(256) void k_out(const float* __restrict__ agg, const float* __restrict__ h,
                                             const float* __restrict__ wl, const float* __restrict__ bl,
                                             const float* __restrict__ wr, float* __restrict__ out, int n) {
    __shared__ float sA[16][HIDC];
    __shared__ float sH[16][HIDC];
    __shared__ float sO[16][48];
    int t = threadIdx.x;
    int brow = blockIdx.x * 16;
    for (int idx = t; idx < 16 * HIDC; idx += 256) {
        int r = idx >> 7, c = idx & 127;
        int row = brow + r;
        float a = 0.f, hv = 0.f;
        if (row < n) {
            a = agg[(size_t)row * HIDC + c];
            hv = h[(size_t)row * HIDC + c];
        }
        sA[r][c] = a;
        sH[r][c] = hv;
    }
    __syncthreads();
    int q = t >> 6, j = t & 63;   // rows q*4..q*4+3, col j (j<47 active)
    if (j < OUTC) {
        float acc[4] = {0, 0, 0, 0};
#pragma unroll 2
        for (int k0 = 0; k0 < HIDC; k0 += 4) {
            float a_[4][4], h_[4][4];
#pragma unroll
            for (int r = 0; r < 4; r++) {
                float4 t4 = *reinterpret_cast<const float4*>(&sA[q * 4 + r][k0]);
                a_[r][0] = t4.x; a_[r][1] = t4.y; a_[r][2] = t4.z; a_[r][3] = t4.w;
                float4 t5 = *reinterpret_cast<const float4*>(&sH[q * 4 + r][k0]);
                h_[r][0] = t5.x; h_[r][1] = t5.y; h_[r][2] = t5.z; h_[r][3] = t5.w;
            }
#pragma unroll
            for (int kk = 0; kk < 4; kk++) {
                int k = k0 + kk;
                float wlv = wl[k * OUTC + j];
                float wrv = wr[k * OUTC + j];
#pragma unroll
                for (int r = 0; r < 4; r++) acc[r] += a_[r][kk] * wlv + h_[r][kk] * wrv;
            }
        }
        float bv = bl[j];
#pragma unroll
        for (int r = 0; r < 4; r++) sO[q * 4 + r][j] = acc[r] + bv;
    }
    __syncthreads();
    // log_softmax: wave q handles rows q*4..q*4+3
    int lane = t & 63;
#pragma unroll
    for (int r = 0; r < 4; r++) {
        int row = brow + q * 4 + r;
        bool act = (lane < OUTC) && (row < n);
        float val = act ? sO[q * 4 + r][lane] : -INFINITY;
        float m = val;
#pragma unroll
        for (int off = 32; off; off >>= 1) m = fmaxf(m, __shfl_xor(m, off));
        float ex = act ? __expf(val - m) : 0.f;
        float s = ex;
#pragma unroll
        for (int off = 32; off; off >>= 1) s += __shfl_xor(s, off);
        if (act) out[(size_t)row * OUTC + lane] = val - m - logf(s);
    }
}

// ---------------- Launch ----------------

extern "C" void kernel_launch(void* const* d_in, const int* in_sizes, int n_in,
                              void* d_out, int out_size, void* d_ws, size_t ws_size,
                              hipStream_t stream) {
    const float* x        = (const float*)d_in[0];
    const int*   ei       = (const int*)d_in[1];
    const float* inproj_w = (const float*)d_in[2];
    const float* inproj_b = (const float*)d_in[3];
    const float* wl_h     = (const float*)d_in[4];
    const float* bl_h     = (const float*)d_in[5];
    const float* wr_h     = (const float*)d_in[6];
    const float* wl_out   = (const float*)d_in[7];
    const float* bl_out   = (const float*)d_in[8];
    const float* wr_out   = (const float*)d_in[9];
    float* out = (float*)d_out;

    int n  = in_sizes[0] / INC;   // 100000
    int ne = in_sizes[1] / 2;     // 1600000
    const int* src = ei;
    const int* dst = ei + ne;

    char* ws = (char*)d_ws;
    size_t off = 0;
    auto alloc = [&](size_t bytes) -> void* {
        void* p = ws + off;
        off = (off + bytes + 255) & ~(size_t)255;
        return p;
    };
    float* inp    = (float*)alloc((size_t)n * HIDC * 4);
    float* h      = (float*)alloc((size_t)n * HIDC * 4);
    float* agg    = (float*)alloc((size_t)n * HIDC * 4);
    int*   deg    = (int*)alloc((size_t)n * 4);
    float* invdeg = (float*)alloc((size_t)n * 4);
    int*   local_s= (int*)alloc((size_t)n * 4);
    int*   bsum   = (int*)alloc(512 * 4);
    int*   offs   = (int*)alloc((size_t)(n + 1) * 4);
    int*   curs   = (int*)alloc((size_t)n * 4);
    int*   csr    = (int*)alloc((size_t)ne * 4);

    hipMemsetAsync(deg, 0, (size_t)n * 4, stream);
    hipMemsetAsync(curs, 0, (size_t)n * 4, stream);

    int nbE = (ne + 255) / 256;
    int nbN = (n + 255) / 256;    // 391 <= 512, required by k_scan2
    k_deg<<<nbE, 256, 0, stream>>>(dst, deg, ne);
    k_scan1<<<nbN, 256, 0, stream>>>(deg, local_s, bsum, n);
    k_scan2<<<1, 512, 0, stream>>>(bsum, nbN);
    k_scan3<<<nbN, 256, 0, stream>>>(local_s, bsum, offs, n, ne);
    k_invdeg<<<nbN, 256, 0, stream>>>(deg, invdeg, n);
    k_fill<<<nbE, 256, 0, stream>>>(src, dst, offs, curs, csr, ne);

    int nbR = (n + 15) / 16;
    int nbA = (n + 3) / 4;
    k_inproj<<<nbR, 256, 0, stream>>>(x, inproj_w, inproj_b, inp, h, n);
    for (int l = 0; l < 3; ++l) {
        k_agg<<<nbA, 256, 0, stream>>>(h, csr, offs, invdeg, agg, n);
        k_gemm_hid<<<nbR, 256, 0, stream>>>(agg, h, inp,
                                            wl_h + (size_t)l * HIDC * HIDC,
                                            bl_h + (size_t)l * HIDC,
                                            wr_h + (size_t)l * HIDC * HIDC, n);
    }
    k_agg<<<nbA, 256, 0, stream>>>(h, csr, offs, invdeg, agg, n);
    k_out<<<nbR, 256, 0, stream>>>(agg, h, wl_out, bl_out, wr_out, out, n);
}

// Round 4
// 737.842 us; speedup vs baseline: 2.7006x; 1.9238x over previous
//
#include <hip/hip_runtime.h>
#include <math.h>

#define HIDC 128
#define INC 100
#define OUTC 47

typedef __attribute__((ext_vector_type(8))) short short8_t;   // 8 bf16 (4 VGPRs)
typedef __attribute__((ext_vector_type(4))) float f32x4;      // MFMA accumulator

__device__ inline unsigned short f2bf(float f) {
    unsigned u = __builtin_bit_cast(unsigned, f);
    unsigned r = (u + 0x7FFFu + ((u >> 16) & 1u)) >> 16;      // RNE
    return (unsigned short)r;
}
__device__ inline float bf2f(unsigned short s) {
    unsigned u = ((unsigned)s) << 16;
    return __builtin_bit_cast(float, u);
}

// ---------------- CSR build ----------------

__global__ __launch_bounds__(256) void k_deg(const int* __restrict__ dst, int* __restrict__ deg, int ne) {
    int e = blockIdx.x * 256 + threadIdx.x;
    if (e < ne) atomicAdd(&deg[dst[e]], 1);
}

__global__ __launch_bounds__(256) void k_scan1(const int* __restrict__ deg, int* __restrict__ local_s,
                                               int* __restrict__ bsum, int n) {
    __shared__ int s[256];
    int t = threadIdx.x;
    int i = blockIdx.x * 256 + t;
    int v = (i < n) ? deg[i] : 0;
    s[t] = v;
    __syncthreads();
    for (int off = 1; off < 256; off <<= 1) {
        int add = (t >= off) ? s[t - off] : 0;
        __syncthreads();
        s[t] += add;
        __syncthreads();
    }
    if (i < n) local_s[i] = s[t] - v;
    if (t == 255) bsum[blockIdx.x] = s[255];
}

__global__ __launch_bounds__(512) void k_scan2(int* __restrict__ bsum, int nb) {
    __shared__ int s[512];
    int t = threadIdx.x;
    int v = (t < nb) ? bsum[t] : 0;
    s[t] = v;
    __syncthreads();
    for (int off = 1; off < 512; off <<= 1) {
        int add = (t >= off) ? s[t - off] : 0;
        __syncthreads();
        s[t] += add;
        __syncthreads();
    }
    if (t < nb) bsum[t] = s[t] - v;
}

__global__ __launch_bounds__(256) void k_scan3(const int* __restrict__ local_s, const int* __restrict__ bsum,
                                               int* __restrict__ offs, int n, int ne) {
    int i = blockIdx.x * 256 + threadIdx.x;
    if (i < n) offs[i] = local_s[i] + bsum[blockIdx.x];
    if (i == 0) offs[n] = ne;
}

__global__ __launch_bounds__(256) void k_invdeg(const int* __restrict__ deg, float* __restrict__ invdeg, int n) {
    int i = blockIdx.x * 256 + threadIdx.x;
    if (i < n) invdeg[i] = 1.0f / (float)max(deg[i], 1);
}

__global__ __launch_bounds__(256) void k_fill(const int* __restrict__ src, const int* __restrict__ dst,
                                              const int* __restrict__ offs, int* __restrict__ curs,
                                              int* __restrict__ csr, int ne) {
    int e = blockIdx.x * 256 + threadIdx.x;
    if (e < ne) {
        int d = dst[e];
        int p = atomicAdd(&curs[d], 1);
        csr[offs[d] + p] = src[e];
    }
}

// ---------------- Weight transpose+convert: wt[(l*2+s)][n][k] = w_s[l][k][n] as bf16 ----------------

__global__ __launch_bounds__(256) void k_prepw(const float* __restrict__ wl_h, const float* __restrict__ wr_h,
                                               unsigned short* __restrict__ wt) {
    int idx = blockIdx.x * 256 + threadIdx.x;
    if (idx >= 6 * 16384) return;
    int m = idx >> 14, rem = idx & 16383;
    int l = m >> 1, s = m & 1;
    const float* srcm = (s == 0 ? wl_h : wr_h) + (size_t)l * 16384;
    wt[idx] = f2bf(srcm[(rem & 127) * 128 + (rem >> 7)]);
}

// ---------------- Aggregation (pull, mean): wave per node, bf16 rows, 4 edges/iter ----------------

__global__ __launch_bounds__(256) void k_agg(const unsigned short* __restrict__ h, const int* __restrict__ csr,
                                             const int* __restrict__ offs, const float* __restrict__ invdeg,
                                             unsigned short* __restrict__ agg, int n) {
    int wv = threadIdx.x >> 6, lane = threadIdx.x & 63;
    int v = blockIdx.x * 4 + wv;
    if (v >= n) return;
    int q = lane >> 4, c = lane & 15;   // q: edge slot, c: 16B chunk (8 bf16)
    int e0 = offs[v], e1 = offs[v + 1];
    float acc[8] = {0, 0, 0, 0, 0, 0, 0, 0};
    for (int e = e0 + q; e < e1; e += 4) {
        int sidx = csr[e];
        short8_t tv = *reinterpret_cast<const short8_t*>(h + (size_t)sidx * HIDC + c * 8);
#pragma unroll
        for (int i = 0; i < 8; i++) acc[i] += bf2f((unsigned short)tv[i]);
    }
#pragma unroll
    for (int i = 0; i < 8; i++) {
        acc[i] += __shfl_xor(acc[i], 16);
        acc[i] += __shfl_xor(acc[i], 32);
    }
    if (q == 0) {
        float s = invdeg[v];
        unsigned short o[8];
#pragma unroll
        for (int i = 0; i < 8; i++) o[i] = f2bf(acc[i] * s);
        *reinterpret_cast<short8_t*>(agg + (size_t)v * HIDC + c * 8) = *reinterpret_cast<const short8_t*>(o);
    }
}

// ---------------- Input projection: inp = x@W + b (fp32); h = relu(inp) (bf16) ----------------

__global__ __launch_bounds__(256) void k_inproj(const float* __restrict__ x, const float* __restrict__ w,
                                                const float* __restrict__ b, float* __restrict__ inp,
                                                unsigned short* __restrict__ h, int n) {
    __shared__ float sX[16][INC];
    int t = threadIdx.x;
    int brow = blockIdx.x * 16;
    for (int idx = t; idx < 16 * INC; idx += 256) {
        int r = idx / INC, c = idx % INC;
        int row = brow + r;
        sX[r][c] = (row < n) ? x[(size_t)row * INC + c] : 0.f;
    }
    __syncthreads();
    int q = t >> 6, j = t & 63;
    float acc0[4] = {0, 0, 0, 0}, acc1[4] = {0, 0, 0, 0};
#pragma unroll 2
    for (int k0 = 0; k0 < INC; k0 += 4) {
        float a_[4][4];
#pragma unroll
        for (int r = 0; r < 4; r++) {
            float4 t4 = *reinterpret_cast<const float4*>(&sX[q * 4 + r][k0]);
            a_[r][0] = t4.x; a_[r][1] = t4.y; a_[r][2] = t4.z; a_[r][3] = t4.w;
        }
#pragma unroll
        for (int kk = 0; kk < 4; kk++) {
            int k = k0 + kk;
            float w0 = w[k * HIDC + j];
            float w1 = w[k * HIDC + j + 64];
#pragma unroll
            for (int r = 0; r < 4; r++) {
                acc0[r] += a_[r][kk] * w0;
                acc1[r] += a_[r][kk] * w1;
            }
        }
    }
    float b0 = b[j], b1 = b[j + 64];
#pragma unroll
    for (int r = 0; r < 4; r++) {
        int row = brow + q * 4 + r;
        if (row < n) {
            float v0 = acc0[r] + b0, v1 = acc1[r] + b1;
            inp[(size_t)row * HIDC + j] = v0;
            inp[(size_t)row * HIDC + j + 64] = v1;
            h[(size_t)row * HIDC + j] = f2bf(fmaxf(v0, 0.f));
            h[(size_t)row * HIDC + j + 64] = f2bf(fmaxf(v1, 0.f));
        }
    }
}

// ---------------- Hidden SAGE layer via MFMA: h = relu(agg@wl + bl + h@wr) + 0.2*inp ----------------
// 32-row tile, 4 waves; wave w owns cols [32w,32w+32). Weights pre-transposed (wt[n][k]) in regs.
// A/B k-ordering is identical on both operands => exact for any HW k-permutation.

__global__ __launch_bounds__(256) void k_sage_mfma(const unsigned short* __restrict__ agg,
                                                   unsigned short* __restrict__ h,
                                                   const float* __restrict__ inp,
                                                   const unsigned short* __restrict__ wt,  // [2][128][128]
                                                   const float* __restrict__ bl, int n) {
    __shared__ unsigned short sA[2][32 * 128];
    int t = threadIdx.x;
    int w = t >> 6, lane = t & 63;
    int cc = lane & 15, kg = lane >> 4;
    int row0 = blockIdx.x * 32;

    // preload B fragments: [s=mat][ci=coltile][ks]
    short8_t bfrag[2][2][4];
#pragma unroll
    for (int s = 0; s < 2; s++)
#pragma unroll
        for (int ci = 0; ci < 2; ci++) {
            int ncol = 32 * w + ci * 16 + cc;
            const unsigned short* bp = wt + s * 16384 + ncol * 128 + kg * 8;
#pragma unroll
            for (int ks = 0; ks < 4; ks++)
                bfrag[s][ci][ks] = *reinterpret_cast<const short8_t*>(bp + ks * 32);
        }

    // stage agg+h rows into LDS, XOR-swizzled (256B rows -> (row&7)<<4)
    for (int c = t; c < 512; c += 256) {
        int r = c >> 4, g = c & 15;
        int row = row0 + r;
        unsigned byte = r * 256 + (((unsigned)g * 16) ^ (((unsigned)r & 7) << 4));
        short8_t va = {0, 0, 0, 0, 0, 0, 0, 0}, vh = va;
        if (row < n) {
            va = *reinterpret_cast<const short8_t*>(agg + (size_t)row * HIDC + g * 8);
            vh = *reinterpret_cast<const short8_t*>(h + (size_t)row * HIDC + g * 8);
        }
        *reinterpret_cast<short8_t*>(reinterpret_cast<char*>(&sA[0][0]) + byte) = va;
        *reinterpret_cast<short8_t*>(reinterpret_cast<char*>(&sA[1][0]) + byte) = vh;
    }
    __syncthreads();

    f32x4 acc[2][2];
#pragma unroll
    for (int rt = 0; rt < 2; rt++)
#pragma unroll
        for (int ci = 0; ci < 2; ci++) acc[rt][ci] = (f32x4){0.f, 0.f, 0.f, 0.f};

#pragma unroll
    for (int ks = 0; ks < 4; ks++) {
        short8_t af[2][2];
#pragma unroll
        for (int s = 0; s < 2; s++)
#pragma unroll
            for (int rt = 0; rt < 2; rt++) {
                int r = rt * 16 + cc;
                unsigned byte = r * 256 + (((unsigned)(ks * 64 + kg * 16)) ^ (((unsigned)r & 7) << 4));
                af[s][rt] = *reinterpret_cast<const short8_t*>(reinterpret_cast<const char*>(&sA[s][0]) + byte);
            }
#pragma unroll
        for (int s = 0; s < 2; s++)
#pragma unroll
            for (int rt = 0; rt < 2; rt++)
#pragma unroll
                for (int ci = 0; ci < 2; ci++)
                    acc[rt][ci] = __builtin_amdgcn_mfma_f32_16x16x32_bf16(af[s][rt], bfrag[s][ci][ks],
                                                                          acc[rt][ci], 0, 0, 0);
    }

    // epilogue: C/D layout col=lane&15, row=(lane>>4)*4+reg (HW-verified)
#pragma unroll
    for (int rt = 0; rt < 2; rt++)
#pragma unroll
        for (int ci = 0; ci < 2; ci++) {
            int col = 32 * w + ci * 16 + cc;
            float bv = bl[col];
#pragma unroll
            for (int reg = 0; reg < 4; reg++) {
                int row = row0 + rt * 16 + kg * 4 + reg;
                if (row < n) {
                    float v = acc[rt][ci][reg] + bv;
                    v = fmaxf(v, 0.f) + 0.2f * inp[(size_t)row * HIDC + col];
                    h[(size_t)row * HIDC + col] = f2bf(v);
                }
            }
        }
}

// ---------------- Output layer (tiled GEMM fp32) + log_softmax; bf16 inputs ----------------

__global__ __launch_bounds__(256) void k_out(const unsigned short* __restrict__ agg,
                                             const unsigned short* __restrict__ h,
                                             const float* __restrict__ wl, const float* __restrict__ bl,
                                             const float* __restrict__ wr, float* __restrict__ out, int n) {
    __shared__ float sA[16][HIDC];
    __shared__ float sH[16][HIDC];
    __shared__ float sO[16][48];
    int t = threadIdx.x;
    int brow = blockIdx.x * 16;
    for (int idx = t; idx < 256; idx += 256) {
        int r = idx >> 4, g = idx & 15;
        int row = brow + r;
        short8_t va = {0, 0, 0, 0, 0, 0, 0, 0}, vh = va;
        if (row < n) {
            va = *reinterpret_cast<const short8_t*>(agg + (size_t)row * HIDC + g * 8);
            vh = *reinterpret_cast<const short8_t*>(h + (size_t)row * HIDC + g * 8);
        }
#pragma unroll
        for (int i = 0; i < 8; i++) {
            sA[r][g * 8 + i] = bf2f((unsigned short)va[i]);
            sH[r][g * 8 + i] = bf2f((unsigned short)vh[i]);
        }
    }
    __syncthreads();
    int q = t >> 6, j = t & 63;
    if (j < OUTC) {
        float acc[4] = {0, 0, 0, 0};
#pragma unroll 2
        for (int k0 = 0; k0 < HIDC; k0 += 4) {
            float a_[4][4], h_[4][4];
#pragma unroll
            for (int r = 0; r < 4; r++) {
                float4 t4 = *reinterpret_cast<const float4*>(&sA[q * 4 + r][k0]);
                a_[r][0] = t4.x; a_[r][1] = t4.y; a_[r][2] = t4.z; a_[r][3] = t4.w;
                float4 t5 = *reinterpret_cast<const float4*>(&sH[q * 4 + r][k0]);
                h_[r][0] = t5.x; h_[r][1] = t5.y; h_[r][2] = t5.z; h_[r][3] = t5.w;
            }
#pragma unroll
            for (int kk = 0; kk < 4; kk++) {
                int k = k0 + kk;
                float wlv = wl[k * OUTC + j];
                float wrv = wr[k * OUTC + j];
#pragma unroll
                for (int r = 0; r < 4; r++) acc[r] += a_[r][kk] * wlv + h_[r][kk] * wrv;
            }
        }
        float bv = bl[j];
#pragma unroll
        for (int r = 0; r < 4; r++) sO[q * 4 + r][j] = acc[r] + bv;
    }
    __syncthreads();
    int lane = t & 63;
#pragma unroll
    for (int r = 0; r < 4; r++) {
        int row = brow + q * 4 + r;
        bool act = (lane < OUTC) && (row < n);
        float val = act ? sO[q * 4 + r][lane] : -INFINITY;
        float m = val;
#pragma unroll
        for (int off = 32; off; off >>= 1) m = fmaxf(m, __shfl_xor(m, off));
        float ex = act ? __expf(val - m) : 0.f;
        float s = ex;
#pragma unroll
        for (int off = 32; off; off >>= 1) s += __shfl_xor(s, off);
        if (act) out[(size_t)row * OUTC + lane] = val - m - logf(s);
    }
}

// ---------------- Launch ----------------

extern "C" void kernel_launch(void* const* d_in, const int* in_sizes, int n_in,
                              void* d_out, int out_size, void* d_ws, size_t ws_size,
                              hipStream_t stream) {
    const float* x        = (const float*)d_in[0];
    const int*   ei       = (const int*)d_in[1];
    const float* inproj_w = (const float*)d_in[2];
    const float* inproj_b = (const float*)d_in[3];
    const float* wl_h     = (const float*)d_in[4];
    const float* bl_h     = (const float*)d_in[5];
    const float* wr_h     = (const float*)d_in[6];
    const float* wl_out   = (const float*)d_in[7];
    const float* bl_out   = (const float*)d_in[8];
    const float* wr_out   = (const float*)d_in[9];
    float* out = (float*)d_out;

    int n  = in_sizes[0] / INC;   // 100000
    int ne = in_sizes[1] / 2;     // 1600000
    const int* src = ei;
    const int* dst = ei + ne;

    char* ws = (char*)d_ws;
    size_t off = 0;
    auto alloc = [&](size_t bytes) -> void* {
        void* p = ws + off;
        off = (off + bytes + 255) & ~(size_t)255;
        return p;
    };
    float*          inp    = (float*)alloc((size_t)n * HIDC * 4);
    unsigned short* h      = (unsigned short*)alloc((size_t)n * HIDC * 2);
    unsigned short* agg    = (unsigned short*)alloc((size_t)n * HIDC * 2);
    unsigned short* wt     = (unsigned short*)alloc((size_t)6 * 16384 * 2);
    int*   deg    = (int*)alloc((size_t)n * 4);
    float* invdeg = (float*)alloc((size_t)n * 4);
    int*   local_s= (int*)alloc((size_t)n * 4);
    int*   bsum   = (int*)alloc(512 * 4);
    int*   offs   = (int*)alloc((size_t)(n + 1) * 4);
    int*   curs   = (int*)alloc((size_t)n * 4);
    int*   csr    = (int*)alloc((size_t)ne * 4);

    hipMemsetAsync(deg, 0, (size_t)n * 4, stream);
    hipMemsetAsync(curs, 0, (size_t)n * 4, stream);

    int nbE = (ne + 255) / 256;
    int nbN = (n + 255) / 256;
    k_deg<<<nbE, 256, 0, stream>>>(dst, deg, ne);
    k_scan1<<<nbN, 256, 0, stream>>>(deg, local_s, bsum, n);
    k_scan2<<<1, 512, 0, stream>>>(bsum, nbN);
    k_scan3<<<nbN, 256, 0, stream>>>(local_s, bsum, offs, n, ne);
    k_invdeg<<<nbN, 256, 0, stream>>>(deg, invdeg, n);
    k_fill<<<nbE, 256, 0, stream>>>(src, dst, offs, curs, csr, ne);
    k_prepw<<<(6 * 16384 + 255) / 256, 256, 0, stream>>>(wl_h, wr_h, wt);

    int nbR = (n + 15) / 16;
    int nbA = (n + 3) / 4;
    int nbT = (n + 31) / 32;
    k_inproj<<<nbR, 256, 0, stream>>>(x, inproj_w, inproj_b, inp, h, n);
    for (int l = 0; l < 3; ++l) {
        k_agg<<<nbA, 256, 0, stream>>>(h, csr, offs, invdeg, agg, n);
        k_sage_mfma<<<nbT, 256, 0, stream>>>(agg, h, inp, wt + (size_t)l * 2 * 16384,
                                             bl_h + (size_t)l * HIDC, n);
    }
    k_agg<<<nbA, 256, 0, stream>>>(h, csr, offs, invdeg, agg, n);
    k_out<<<nbR, 256, 0, stream>>>(agg, h, wl_out, bl_out, wr_out, out, n);
}

// Round 5
// 642.334 us; speedup vs baseline: 3.1022x; 1.1487x over previous
//
#include <hip/hip_runtime.h>
#include <math.h>

#define HIDC 128
#define INC 100
#define OUTC 47

typedef __attribute__((ext_vector_type(8))) short short8_t;   // 8 bf16 (4 VGPRs)
typedef __attribute__((ext_vector_type(4))) float f32x4;      // MFMA accumulator

__device__ inline unsigned short f2bf(float f) {
    unsigned u = __builtin_bit_cast(unsigned, f);
    unsigned r = (u + 0x7FFFu + ((u >> 16) & 1u)) >> 16;      // RNE
    return (unsigned short)r;
}
__device__ inline float bf2f(unsigned short s) {
    unsigned u = ((unsigned)s) << 16;
    return __builtin_bit_cast(float, u);
}

// ---------------- CSR build ----------------

__global__ __launch_bounds__(256) void k_deg(const int* __restrict__ dst, int* __restrict__ deg, int ne) {
    int e = blockIdx.x * 256 + threadIdx.x;
    if (e < ne) atomicAdd(&deg[dst[e]], 1);
}

__global__ __launch_bounds__(256) void k_scan1(const int* __restrict__ deg, int* __restrict__ local_s,
                                               int* __restrict__ bsum, int n) {
    __shared__ int s[256];
    int t = threadIdx.x;
    int i = blockIdx.x * 256 + t;
    int v = (i < n) ? deg[i] : 0;
    s[t] = v;
    __syncthreads();
    for (int off = 1; off < 256; off <<= 1) {
        int add = (t >= off) ? s[t - off] : 0;
        __syncthreads();
        s[t] += add;
        __syncthreads();
    }
    if (i < n) local_s[i] = s[t] - v;
    if (t == 255) bsum[blockIdx.x] = s[255];
}

__global__ __launch_bounds__(512) void k_scan2(int* __restrict__ bsum, int nb) {
    __shared__ int s[512];
    int t = threadIdx.x;
    int v = (t < nb) ? bsum[t] : 0;
    s[t] = v;
    __syncthreads();
    for (int off = 1; off < 512; off <<= 1) {
        int add = (t >= off) ? s[t - off] : 0;
        __syncthreads();
        s[t] += add;
        __syncthreads();
    }
    if (t < nb) bsum[t] = s[t] - v;
}

__global__ __launch_bounds__(256) void k_scan3(const int* __restrict__ local_s, const int* __restrict__ bsum,
                                               int* __restrict__ offs, int n, int ne) {
    int i = blockIdx.x * 256 + threadIdx.x;
    if (i < n) offs[i] = local_s[i] + bsum[blockIdx.x];
    if (i == 0) offs[n] = ne;
}

__global__ __launch_bounds__(256) void k_invdeg(const int* __restrict__ deg, float* __restrict__ invdeg, int n) {
    int i = blockIdx.x * 256 + threadIdx.x;
    if (i < n) invdeg[i] = 1.0f / (float)max(deg[i], 1);
}

__global__ __launch_bounds__(256) void k_fill(const int* __restrict__ src, const int* __restrict__ dst,
                                              const int* __restrict__ offs, int* __restrict__ curs,
                                              int* __restrict__ csr, int ne) {
    int e = blockIdx.x * 256 + threadIdx.x;
    if (e < ne) {
        int d = dst[e];
        int p = atomicAdd(&curs[d], 1);
        csr[offs[d] + p] = src[e];
    }
}

// ---------------- Weight transpose+convert: hidden wt[(l*2+s)][n][k] bf16 ----------------

__global__ __launch_bounds__(256) void k_prepw(const float* __restrict__ wl_h, const float* __restrict__ wr_h,
                                               unsigned short* __restrict__ wt) {
    int idx = blockIdx.x * 256 + threadIdx.x;
    if (idx >= 6 * 16384) return;
    int m = idx >> 14, rem = idx & 16383;
    int l = m >> 1, s = m & 1;
    const float* srcm = (s == 0 ? wl_h : wr_h) + (size_t)l * 16384;
    wt[idx] = f2bf(srcm[(rem & 127) * 128 + (rem >> 7)]);
}

// out weights: wt2[s][nc][k], nc in [0,48) padded (col 47 = 0), k in [0,128)
__global__ __launch_bounds__(256) void k_prepw_out(const float* __restrict__ wl_out,
                                                   const float* __restrict__ wr_out,
                                                   unsigned short* __restrict__ wt2) {
    int idx = blockIdx.x * 256 + threadIdx.x;
    if (idx >= 2 * 48 * 128) return;
    int s = idx / (48 * 128), rem = idx % (48 * 128);
    int nc = rem >> 7, k = rem & 127;
    const float* srcm = (s == 0) ? wl_out : wr_out;
    wt2[idx] = (nc < OUTC) ? f2bf(srcm[k * OUTC + nc]) : 0;
}

// ---------------- Aggregation (pull, mean): wave per node, bf16 rows, 8 edges/iter ----------------

__global__ __launch_bounds__(256) void k_agg(const unsigned short* __restrict__ h, const int* __restrict__ csr,
                                             const int* __restrict__ offs, const float* __restrict__ invdeg,
                                             unsigned short* __restrict__ agg, int n) {
    int wv = threadIdx.x >> 6, lane = threadIdx.x & 63;
    int v = blockIdx.x * 4 + wv;
    if (v >= n) return;
    int q = lane >> 4, c = lane & 15;   // q: edge slot, c: 16B chunk (8 bf16)
    int e0 = offs[v], e1 = offs[v + 1];
    float acc[8] = {0, 0, 0, 0, 0, 0, 0, 0};
    for (int e = e0 + q; e < e1; e += 8) {
        int s0 = csr[e];
        bool has2 = (e + 4) < e1;
        int s1 = has2 ? csr[e + 4] : s0;
        short8_t t0 = *reinterpret_cast<const short8_t*>(h + (size_t)s0 * HIDC + c * 8);
        short8_t t1 = *reinterpret_cast<const short8_t*>(h + (size_t)s1 * HIDC + c * 8);
#pragma unroll
        for (int i = 0; i < 8; i++) {
            acc[i] += bf2f((unsigned short)t0[i]);
            if (has2) acc[i] += bf2f((unsigned short)t1[i]);
        }
    }
#pragma unroll
    for (int i = 0; i < 8; i++) {
        acc[i] += __shfl_xor(acc[i], 16);
        acc[i] += __shfl_xor(acc[i], 32);
    }
    if (q == 0) {
        float s = invdeg[v];
        unsigned short o[8];
#pragma unroll
        for (int i = 0; i < 8; i++) o[i] = f2bf(acc[i] * s);
        *reinterpret_cast<short8_t*>(agg + (size_t)v * HIDC + c * 8) = *reinterpret_cast<const short8_t*>(o);
    }
}

// ---------------- Input projection: inp = x@W + b (fp32); h = relu(inp) (bf16) ----------------

__global__ __launch_bounds__(256) void k_inproj(const float* __restrict__ x, const float* __restrict__ w,
                                                const float* __restrict__ b, float* __restrict__ inp,
                                                unsigned short* __restrict__ h, int n) {
    __shared__ float sX[16][INC];
    int t = threadIdx.x;
    int brow = blockIdx.x * 16;
    for (int idx = t; idx < 16 * INC; idx += 256) {
        int r = idx / INC, c = idx % INC;
        int row = brow + r;
        sX[r][c] = (row < n) ? x[(size_t)row * INC + c] : 0.f;
    }
    __syncthreads();
    int q = t >> 6, j = t & 63;
    float acc0[4] = {0, 0, 0, 0}, acc1[4] = {0, 0, 0, 0};
#pragma unroll 2
    for (int k0 = 0; k0 < INC; k0 += 4) {
        float a_[4][4];
#pragma unroll
        for (int r = 0; r < 4; r++) {
            float4 t4 = *reinterpret_cast<const float4*>(&sX[q * 4 + r][k0]);
            a_[r][0] = t4.x; a_[r][1] = t4.y; a_[r][2] = t4.z; a_[r][3] = t4.w;
        }
#pragma unroll
        for (int kk = 0; kk < 4; kk++) {
            int k = k0 + kk;
            float w0 = w[k * HIDC + j];
            float w1 = w[k * HIDC + j + 64];
#pragma unroll
            for (int r = 0; r < 4; r++) {
                acc0[r] += a_[r][kk] * w0;
                acc1[r] += a_[r][kk] * w1;
            }
        }
    }
    float b0 = b[j], b1 = b[j + 64];
#pragma unroll
    for (int r = 0; r < 4; r++) {
        int row = brow + q * 4 + r;
        if (row < n) {
            float v0 = acc0[r] + b0, v1 = acc1[r] + b1;
            inp[(size_t)row * HIDC + j] = v0;
            inp[(size_t)row * HIDC + j + 64] = v1;
            h[(size_t)row * HIDC + j] = f2bf(fmaxf(v0, 0.f));
            h[(size_t)row * HIDC + j + 64] = f2bf(fmaxf(v1, 0.f));
        }
    }
}

// ---------------- Hidden SAGE layer via MFMA ----------------

__global__ __launch_bounds__(256) void k_sage_mfma(const unsigned short* __restrict__ agg,
                                                   unsigned short* __restrict__ h,
                                                   const float* __restrict__ inp,
                                                   const unsigned short* __restrict__ wt,  // [2][128][128]
                                                   const float* __restrict__ bl, int n) {
    __shared__ unsigned short sA[2][32 * 128];
    int t = threadIdx.x;
    int w = t >> 6, lane = t & 63;
    int cc = lane & 15, kg = lane >> 4;
    int row0 = blockIdx.x * 32;

    short8_t bfrag[2][2][4];
#pragma unroll
    for (int s = 0; s < 2; s++)
#pragma unroll
        for (int ci = 0; ci < 2; ci++) {
            int ncol = 32 * w + ci * 16 + cc;
            const unsigned short* bp = wt + s * 16384 + ncol * 128 + kg * 8;
#pragma unroll
            for (int ks = 0; ks < 4; ks++)
                bfrag[s][ci][ks] = *reinterpret_cast<const short8_t*>(bp + ks * 32);
        }

    for (int c = t; c < 512; c += 256) {
        int r = c >> 4, g = c & 15;
        int row = row0 + r;
        unsigned byte = r * 256 + (((unsigned)g * 16) ^ (((unsigned)r & 7) << 4));
        short8_t va = {0, 0, 0, 0, 0, 0, 0, 0}, vh = va;
        if (row < n) {
            va = *reinterpret_cast<const short8_t*>(agg + (size_t)row * HIDC + g * 8);
            vh = *reinterpret_cast<const short8_t*>(h + (size_t)row * HIDC + g * 8);
        }
        *reinterpret_cast<short8_t*>(reinterpret_cast<char*>(&sA[0][0]) + byte) = va;
        *reinterpret_cast<short8_t*>(reinterpret_cast<char*>(&sA[1][0]) + byte) = vh;
    }
    __syncthreads();

    f32x4 acc[2][2];
#pragma unroll
    for (int rt = 0; rt < 2; rt++)
#pragma unroll
        for (int ci = 0; ci < 2; ci++) acc[rt][ci] = (f32x4){0.f, 0.f, 0.f, 0.f};

#pragma unroll
    for (int ks = 0; ks < 4; ks++) {
        short8_t af[2][2];
#pragma unroll
        for (int s = 0; s < 2; s++)
#pragma unroll
            for (int rt = 0; rt < 2; rt++) {
                int r = rt * 16 + cc;
                unsigned byte = r * 256 + (((unsigned)(ks * 64 + kg * 16)) ^ (((unsigned)r & 7) << 4));
                af[s][rt] = *reinterpret_cast<const short8_t*>(reinterpret_cast<const char*>(&sA[s][0]) + byte);
            }
#pragma unroll
        for (int s = 0; s < 2; s++)
#pragma unroll
            for (int rt = 0; rt < 2; rt++)
#pragma unroll
                for (int ci = 0; ci < 2; ci++)
                    acc[rt][ci] = __builtin_amdgcn_mfma_f32_16x16x32_bf16(af[s][rt], bfrag[s][ci][ks],
                                                                          acc[rt][ci], 0, 0, 0);
    }

#pragma unroll
    for (int rt = 0; rt < 2; rt++)
#pragma unroll
        for (int ci = 0; ci < 2; ci++) {
            int col = 32 * w + ci * 16 + cc;
            float bv = bl[col];
#pragma unroll
            for (int reg = 0; reg < 4; reg++) {
                int row = row0 + rt * 16 + kg * 4 + reg;
                if (row < n) {
                    float v = acc[rt][ci][reg] + bv;
                    v = fmaxf(v, 0.f) + 0.2f * inp[(size_t)row * HIDC + col];
                    h[(size_t)row * HIDC + col] = f2bf(v);
                }
            }
        }
}

// ---------------- Output layer via MFMA + in-register log_softmax ----------------
// 64-row block, 4 waves; wave w owns rows [w*16, w*16+16), all 3 col-tiles (48 cols, col47 pad).

__global__ __launch_bounds__(256) void k_out_mfma(const unsigned short* __restrict__ agg,
                                                  const unsigned short* __restrict__ h,
                                                  const unsigned short* __restrict__ wt2,  // [2][48][128]
                                                  const float* __restrict__ bl,
                                                  float* __restrict__ out, int n) {
    __shared__ unsigned short sA[2][64 * 128];
    int t = threadIdx.x;
    int w = t >> 6, lane = t & 63;
    int cc = lane & 15, kg = lane >> 4;
    int row0 = blockIdx.x * 64;

    // B fragments in registers: [s][ci][ks]
    short8_t bfrag[2][3][4];
#pragma unroll
    for (int s = 0; s < 2; s++)
#pragma unroll
        for (int ci = 0; ci < 3; ci++) {
            const unsigned short* bp = wt2 + s * (48 * 128) + (ci * 16 + cc) * 128 + kg * 8;
#pragma unroll
            for (int ks = 0; ks < 4; ks++)
                bfrag[s][ci][ks] = *reinterpret_cast<const short8_t*>(bp + ks * 32);
        }

    // stage 64 rows of agg+h, swizzled
    for (int c = t; c < 1024; c += 256) {
        int r = c >> 4, g = c & 15;
        int row = row0 + r;
        unsigned byte = r * 256 + (((unsigned)g * 16) ^ (((unsigned)r & 7) << 4));
        short8_t va = {0, 0, 0, 0, 0, 0, 0, 0}, vh = va;
        if (row < n) {
            va = *reinterpret_cast<const short8_t*>(agg + (size_t)row * HIDC + g * 8);
            vh = *reinterpret_cast<const short8_t*>(h + (size_t)row * HIDC + g * 8);
        }
        *reinterpret_cast<short8_t*>(reinterpret_cast<char*>(&sA[0][0]) + byte) = va;
        *reinterpret_cast<short8_t*>(reinterpret_cast<char*>(&sA[1][0]) + byte) = vh;
    }
    __syncthreads();

    f32x4 acc[3];
#pragma unroll
    for (int ci = 0; ci < 3; ci++) acc[ci] = (f32x4){0.f, 0.f, 0.f, 0.f};

#pragma unroll
    for (int ks = 0; ks < 4; ks++) {
        short8_t af[2];
        int r = w * 16 + cc;
        unsigned byte = r * 256 + (((unsigned)(ks * 64 + kg * 16)) ^ (((unsigned)r & 7) << 4));
#pragma unroll
        for (int s = 0; s < 2; s++)
            af[s] = *reinterpret_cast<const short8_t*>(reinterpret_cast<const char*>(&sA[s][0]) + byte);
#pragma unroll
        for (int s = 0; s < 2; s++)
#pragma unroll
            for (int ci = 0; ci < 3; ci++)
                acc[ci] = __builtin_amdgcn_mfma_f32_16x16x32_bf16(af[s], bfrag[s][ci][ks], acc[ci], 0, 0, 0);
    }

    // epilogue: lane holds cols {cc, cc+16, cc+32} for rows w*16 + kg*4 + reg
#pragma unroll
    for (int reg = 0; reg < 4; reg++) {
        int row = row0 + w * 16 + kg * 4 + reg;
        float val[3];
        float m = -INFINITY;
#pragma unroll
        for (int ci = 0; ci < 3; ci++) {
            int col = ci * 16 + cc;
            val[ci] = (col < OUTC) ? (acc[ci][reg] + bl[col]) : -INFINITY;
            m = fmaxf(m, val[ci]);
        }
#pragma unroll
        for (int off = 1; off < 16; off <<= 1) m = fmaxf(m, __shfl_xor(m, off));
        float s = 0.f;
#pragma unroll
        for (int ci = 0; ci < 3; ci++) {
            int col = ci * 16 + cc;
            if (col < OUTC) s += __expf(val[ci] - m);
        }
#pragma unroll
        for (int off = 1; off < 16; off <<= 1) s += __shfl_xor(s, off);
        float lse = m + logf(s);
        if (row < n) {
#pragma unroll
            for (int ci = 0; ci < 3; ci++) {
                int col = ci * 16 + cc;
                if (col < OUTC) out[(size_t)row * OUTC + col] = val[ci] - lse;
            }
        }
    }
}

// ---------------- Launch ----------------

extern "C" void kernel_launch(void* const* d_in, const int* in_sizes, int n_in,
                              void* d_out, int out_size, void* d_ws, size_t ws_size,
                              hipStream_t stream) {
    const float* x        = (const float*)d_in[0];
    const int*   ei       = (const int*)d_in[1];
    const float* inproj_w = (const float*)d_in[2];
    const float* inproj_b = (const float*)d_in[3];
    const float* wl_h     = (const float*)d_in[4];
    const float* bl_h     = (const float*)d_in[5];
    const float* wr_h     = (const float*)d_in[6];
    const float* wl_out   = (const float*)d_in[7];
    const float* bl_out   = (const float*)d_in[8];
    const float* wr_out   = (const float*)d_in[9];
    float* out = (float*)d_out;

    int n  = in_sizes[0] / INC;   // 100000
    int ne = in_sizes[1] / 2;     // 1600000
    const int* src = ei;
    const int* dst = ei + ne;

    char* ws = (char*)d_ws;
    size_t off = 0;
    auto alloc = [&](size_t bytes) -> void* {
        void* p = ws + off;
        off = (off + bytes + 255) & ~(size_t)255;
        return p;
    };
    float*          inp    = (float*)alloc((size_t)n * HIDC * 4);
    unsigned short* h      = (unsigned short*)alloc((size_t)n * HIDC * 2);
    unsigned short* agg    = (unsigned short*)alloc((size_t)n * HIDC * 2);
    unsigned short* wt     = (unsigned short*)alloc((size_t)6 * 16384 * 2);
    unsigned short* wt2    = (unsigned short*)alloc((size_t)2 * 48 * 128 * 2);
    int*   deg    = (int*)alloc((size_t)n * 4);
    float* invdeg = (float*)alloc((size_t)n * 4);
    int*   local_s= (int*)alloc((size_t)n * 4);
    int*   bsum   = (int*)alloc(512 * 4);
    int*   offs   = (int*)alloc((size_t)(n + 1) * 4);
    int*   curs   = (int*)alloc((size_t)n * 4);
    int*   csr    = (int*)alloc((size_t)ne * 4);

    hipMemsetAsync(deg, 0, (size_t)n * 4, stream);
    hipMemsetAsync(curs, 0, (size_t)n * 4, stream);

    int nbE = (ne + 255) / 256;
    int nbN = (n + 255) / 256;
    k_deg<<<nbE, 256, 0, stream>>>(dst, deg, ne);
    k_scan1<<<nbN, 256, 0, stream>>>(deg, local_s, bsum, n);
    k_scan2<<<1, 512, 0, stream>>>(bsum, nbN);
    k_scan3<<<nbN, 256, 0, stream>>>(local_s, bsum, offs, n, ne);
    k_invdeg<<<nbN, 256, 0, stream>>>(deg, invdeg, n);
    k_fill<<<nbE, 256, 0, stream>>>(src, dst, offs, curs, csr, ne);
    k_prepw<<<(6 * 16384 + 255) / 256, 256, 0, stream>>>(wl_h, wr_h, wt);
    k_prepw_out<<<(2 * 48 * 128 + 255) / 256, 256, 0, stream>>>(wl_out, wr_out, wt2);

    int nbR = (n + 15) / 16;
    int nbA = (n + 3) / 4;
    int nbT = (n + 31) / 32;
    int nbO = (n + 63) / 64;
    k_inproj<<<nbR, 256, 0, stream>>>(x, inproj_w, inproj_b, inp, h, n);
    for (int l = 0; l < 3; ++l) {
        k_agg<<<nbA, 256, 0, stream>>>(h, csr, offs, invdeg, agg, n);
        k_sage_mfma<<<nbT, 256, 0, stream>>>(agg, h, inp, wt + (size_t)l * 2 * 16384,
                                             bl_h + (size_t)l * HIDC, n);
    }
    k_agg<<<nbA, 256, 0, stream>>>(h, csr, offs, invdeg, agg, n);
    k_out_mfma<<<nbO, 256, 0, stream>>>(agg, h, wt2, bl_out, out, n);
}

// Round 6
// 631.731 us; speedup vs baseline: 3.1543x; 1.0168x over previous
//
#include <hip/hip_runtime.h>
#include <math.h>

#define HIDC 128
#define INC 100
#define OUTC 47

typedef __attribute__((ext_vector_type(8))) short short8_t;   // 8 bf16 (4 VGPRs)
typedef __attribute__((ext_vector_type(4))) float f32x4;      // MFMA accumulator

__device__ inline unsigned short f2bf(float f) {
    unsigned u = __builtin_bit_cast(unsigned, f);
    unsigned r = (u + 0x7FFFu + ((u >> 16) & 1u)) >> 16;      // RNE
    return (unsigned short)r;
}
__device__ inline float bf2f(unsigned short s) {
    unsigned u = ((unsigned)s) << 16;
    return __builtin_bit_cast(float, u);
}

// ---------------- CSR build ----------------

__global__ __launch_bounds__(256) void k_deg(const int* __restrict__ dst, int* __restrict__ deg, int ne) {
    int e = blockIdx.x * 256 + threadIdx.x;
    if (e < ne) atomicAdd(&deg[dst[e]], 1);
}

__global__ __launch_bounds__(256) void k_scan1(const int* __restrict__ deg, int* __restrict__ local_s,
                                               int* __restrict__ bsum, int n) {
    __shared__ int s[256];
    int t = threadIdx.x;
    int i = blockIdx.x * 256 + t;
    int v = (i < n) ? deg[i] : 0;
    s[t] = v;
    __syncthreads();
    for (int off = 1; off < 256; off <<= 1) {
        int add = (t >= off) ? s[t - off] : 0;
        __syncthreads();
        s[t] += add;
        __syncthreads();
    }
    if (i < n) local_s[i] = s[t] - v;
    if (t == 255) bsum[blockIdx.x] = s[255];
}

__global__ __launch_bounds__(512) void k_scan2(int* __restrict__ bsum, int nb) {
    __shared__ int s[512];
    int t = threadIdx.x;
    int v = (t < nb) ? bsum[t] : 0;
    s[t] = v;
    __syncthreads();
    for (int off = 1; off < 512; off <<= 1) {
        int add = (t >= off) ? s[t - off] : 0;
        __syncthreads();
        s[t] += add;
        __syncthreads();
    }
    if (t < nb) bsum[t] = s[t] - v;
}

__global__ __launch_bounds__(256) void k_scan3(const int* __restrict__ local_s, const int* __restrict__ bsum,
                                               int* __restrict__ offs, int n, int ne) {
    int i = blockIdx.x * 256 + threadIdx.x;
    if (i < n) offs[i] = local_s[i] + bsum[blockIdx.x];
    if (i == 0) offs[n] = ne;
}

__global__ __launch_bounds__(256) void k_invdeg(const int* __restrict__ deg, float* __restrict__ invdeg, int n) {
    int i = blockIdx.x * 256 + threadIdx.x;
    if (i < n) invdeg[i] = 1.0f / (float)max(deg[i], 1);
}

// Partitioned fill: block handles partition p = blockIdx.x & 7 (XCD round-robin)
// over edge chunk blockIdx.x >> 3. Writes land in an 800KB csr slice -> stays in
// that XCD's L2 until full lines are assembled (kills the 16x write amplification).

__global__ __launch_bounds__(256) void k_fill(const int* __restrict__ src, const int* __restrict__ dst,
                                              const int* __restrict__ offs, int* __restrict__ curs,
                                              int* __restrict__ csr, int ne, int psize, int ch) {
    int p = blockIdx.x & 7;
    int chunk = blockIdx.x >> 3;
    int lo = p * psize;
    int e0 = chunk * ch;
    int e1 = min(ne, e0 + ch);
    for (int e = e0 + threadIdx.x; e < e1; e += 256) {
        int d = dst[e];
        if ((unsigned)(d - lo) < (unsigned)psize) {
            int pos = atomicAdd(&curs[d], 1);
            csr[offs[d] + pos] = src[e];
        }
    }
}

// ---------------- Weight transpose+convert: hidden wt[(l*2+s)][n][k] bf16 ----------------

__global__ __launch_bounds__(256) void k_prepw(const float* __restrict__ wl_h, const float* __restrict__ wr_h,
                                               unsigned short* __restrict__ wt) {
    int idx = blockIdx.x * 256 + threadIdx.x;
    if (idx >= 6 * 16384) return;
    int m = idx >> 14, rem = idx & 16383;
    int l = m >> 1, s = m & 1;
    const float* srcm = (s == 0 ? wl_h : wr_h) + (size_t)l * 16384;
    wt[idx] = f2bf(srcm[(rem & 127) * 128 + (rem >> 7)]);
}

// out weights: wt2[s][nc][k], nc in [0,48) padded (col 47 = 0), k in [0,128)
__global__ __launch_bounds__(256) void k_prepw_out(const float* __restrict__ wl_out,
                                                   const float* __restrict__ wr_out,
                                                   unsigned short* __restrict__ wt2) {
    int idx = blockIdx.x * 256 + threadIdx.x;
    if (idx >= 2 * 48 * 128) return;
    int s = idx / (48 * 128), rem = idx % (48 * 128);
    int nc = rem >> 7, k = rem & 127;
    const float* srcm = (s == 0) ? wl_out : wr_out;
    wt2[idx] = (nc < OUTC) ? f2bf(srcm[k * OUTC + nc]) : 0;
}

// ---------------- Aggregation (pull, mean): wave per node, bf16 rows, 8 edges/iter ----------------

__global__ __launch_bounds__(256) void k_agg(const unsigned short* __restrict__ h, const int* __restrict__ csr,
                                             const int* __restrict__ offs, const float* __restrict__ invdeg,
                                             unsigned short* __restrict__ agg, int n) {
    int wv = threadIdx.x >> 6, lane = threadIdx.x & 63;
    int v = blockIdx.x * 4 + wv;
    if (v >= n) return;
    int q = lane >> 4, c = lane & 15;   // q: edge slot, c: 16B chunk (8 bf16)
    int e0 = offs[v], e1 = offs[v + 1];
    float acc[8] = {0, 0, 0, 0, 0, 0, 0, 0};
    for (int e = e0 + q; e < e1; e += 8) {
        int s0 = csr[e];
        bool has2 = (e + 4) < e1;
        int s1 = has2 ? csr[e + 4] : s0;
        short8_t t0 = *reinterpret_cast<const short8_t*>(h + (size_t)s0 * HIDC + c * 8);
        short8_t t1 = *reinterpret_cast<const short8_t*>(h + (size_t)s1 * HIDC + c * 8);
#pragma unroll
        for (int i = 0; i < 8; i++) {
            acc[i] += bf2f((unsigned short)t0[i]);
            if (has2) acc[i] += bf2f((unsigned short)t1[i]);
        }
    }
#pragma unroll
    for (int i = 0; i < 8; i++) {
        acc[i] += __shfl_xor(acc[i], 16);
        acc[i] += __shfl_xor(acc[i], 32);
    }
    if (q == 0) {
        float s = invdeg[v];
        unsigned short o[8];
#pragma unroll
        for (int i = 0; i < 8; i++) o[i] = f2bf(acc[i] * s);
        *reinterpret_cast<short8_t*>(agg + (size_t)v * HIDC + c * 8) = *reinterpret_cast<const short8_t*>(o);
    }
}

// ---------------- Input projection: inp = x@W + b (fp32); h = relu(inp) (bf16) ----------------

__global__ __launch_bounds__(256) void k_inproj(const float* __restrict__ x, const float* __restrict__ w,
                                                const float* __restrict__ b, float* __restrict__ inp,
                                                unsigned short* __restrict__ h, int n) {
    __shared__ float sX[16][INC];
    int t = threadIdx.x;
    int brow = blockIdx.x * 16;
    for (int idx = t; idx < 16 * INC; idx += 256) {
        int r = idx / INC, c = idx % INC;
        int row = brow + r;
        sX[r][c] = (row < n) ? x[(size_t)row * INC + c] : 0.f;
    }
    __syncthreads();
    int q = t >> 6, j = t & 63;
    float acc0[4] = {0, 0, 0, 0}, acc1[4] = {0, 0, 0, 0};
#pragma unroll 2
    for (int k0 = 0; k0 < INC; k0 += 4) {
        float a_[4][4];
#pragma unroll
        for (int r = 0; r < 4; r++) {
            float4 t4 = *reinterpret_cast<const float4*>(&sX[q * 4 + r][k0]);
            a_[r][0] = t4.x; a_[r][1] = t4.y; a_[r][2] = t4.z; a_[r][3] = t4.w;
        }
#pragma unroll
        for (int kk = 0; kk < 4; kk++) {
            int k = k0 + kk;
            float w0 = w[k * HIDC + j];
            float w1 = w[k * HIDC + j + 64];
#pragma unroll
            for (int r = 0; r < 4; r++) {
                acc0[r] += a_[r][kk] * w0;
                acc1[r] += a_[r][kk] * w1;
            }
        }
    }
    float b0 = b[j], b1 = b[j + 64];
#pragma unroll
    for (int r = 0; r < 4; r++) {
        int row = brow + q * 4 + r;
        if (row < n) {
            float v0 = acc0[r] + b0, v1 = acc1[r] + b1;
            inp[(size_t)row * HIDC + j] = v0;
            inp[(size_t)row * HIDC + j + 64] = v1;
            h[(size_t)row * HIDC + j] = f2bf(fmaxf(v0, 0.f));
            h[(size_t)row * HIDC + j + 64] = f2bf(fmaxf(v1, 0.f));
        }
    }
}

// ---------------- Hidden SAGE layer via MFMA ----------------

__global__ __launch_bounds__(256) void k_sage_mfma(const unsigned short* __restrict__ agg,
                                                   unsigned short* __restrict__ h,
                                                   const float* __restrict__ inp,
                                                   const unsigned short* __restrict__ wt,  // [2][128][128]
                                                   const float* __restrict__ bl, int n) {
    __shared__ unsigned short sA[2][32 * 128];
    int t = threadIdx.x;
    int w = t >> 6, lane = t & 63;
    int cc = lane & 15, kg = lane >> 4;
    int row0 = blockIdx.x * 32;

    short8_t bfrag[2][2][4];
#pragma unroll
    for (int s = 0; s < 2; s++)
#pragma unroll
        for (int ci = 0; ci < 2; ci++) {
            int ncol = 32 * w + ci * 16 + cc;
            const unsigned short* bp = wt + s * 16384 + ncol * 128 + kg * 8;
#pragma unroll
            for (int ks = 0; ks < 4; ks++)
                bfrag[s][ci][ks] = *reinterpret_cast<const short8_t*>(bp + ks * 32);
        }

    for (int c = t; c < 512; c += 256) {
        int r = c >> 4, g = c & 15;
        int row = row0 + r;
        unsigned byte = r * 256 + (((unsigned)g * 16) ^ (((unsigned)r & 7) << 4));
        short8_t va = {0, 0, 0, 0, 0, 0, 0, 0}, vh = va;
        if (row < n) {
            va = *reinterpret_cast<const short8_t*>(agg + (size_t)row * HIDC + g * 8);
            vh = *reinterpret_cast<const short8_t*>(h + (size_t)row * HIDC + g * 8);
        }
        *reinterpret_cast<short8_t*>(reinterpret_cast<char*>(&sA[0][0]) + byte) = va;
        *reinterpret_cast<short8_t*>(reinterpret_cast<char*>(&sA[1][0]) + byte) = vh;
    }
    __syncthreads();

    f32x4 acc[2][2];
#pragma unroll
    for (int rt = 0; rt < 2; rt++)
#pragma unroll
        for (int ci = 0; ci < 2; ci++) acc[rt][ci] = (f32x4){0.f, 0.f, 0.f, 0.f};

#pragma unroll
    for (int ks = 0; ks < 4; ks++) {
        short8_t af[2][2];
#pragma unroll
        for (int s = 0; s < 2; s++)
#pragma unroll
            for (int rt = 0; rt < 2; rt++) {
                int r = rt * 16 + cc;
                unsigned byte = r * 256 + (((unsigned)(ks * 64 + kg * 16)) ^ (((unsigned)r & 7) << 4));
                af[s][rt] = *reinterpret_cast<const short8_t*>(reinterpret_cast<const char*>(&sA[s][0]) + byte);
            }
#pragma unroll
        for (int s = 0; s < 2; s++)
#pragma unroll
            for (int rt = 0; rt < 2; rt++)
#pragma unroll
                for (int ci = 0; ci < 2; ci++)
                    acc[rt][ci] = __builtin_amdgcn_mfma_f32_16x16x32_bf16(af[s][rt], bfrag[s][ci][ks],
                                                                          acc[rt][ci], 0, 0, 0);
    }

#pragma unroll
    for (int rt = 0; rt < 2; rt++)
#pragma unroll
        for (int ci = 0; ci < 2; ci++) {
            int col = 32 * w + ci * 16 + cc;
            float bv = bl[col];
#pragma unroll
            for (int reg = 0; reg < 4; reg++) {
                int row = row0 + rt * 16 + kg * 4 + reg;
                if (row < n) {
                    float v = acc[rt][ci][reg] + bv;
                    v = fmaxf(v, 0.f) + 0.2f * inp[(size_t)row * HIDC + col];
                    h[(size_t)row * HIDC + col] = f2bf(v);
                }
            }
        }
}

// ---------------- Output layer via MFMA + in-register log_softmax ----------------

__global__ __launch_bounds__(256) void k_out_mfma(const unsigned short* __restrict__ agg,
                                                  const unsigned short* __restrict__ h,
                                                  const unsigned short* __restrict__ wt2,  // [2][48][128]
                                                  const float* __restrict__ bl,
                                                  float* __restrict__ out, int n) {
    __shared__ unsigned short sA[2][64 * 128];
    int t = threadIdx.x;
    int w = t >> 6, lane = t & 63;
    int cc = lane & 15, kg = lane >> 4;
    int row0 = blockIdx.x * 64;

    short8_t bfrag[2][3][4];
#pragma unroll
    for (int s = 0; s < 2; s++)
#pragma unroll
        for (int ci = 0; ci < 3; ci++) {
            const unsigned short* bp = wt2 + s * (48 * 128) + (ci * 16 + cc) * 128 + kg * 8;
#pragma unroll
            for (int ks = 0; ks < 4; ks++)
                bfrag[s][ci][ks] = *reinterpret_cast<const short8_t*>(bp + ks * 32);
        }

    for (int c = t; c < 1024; c += 256) {
        int r = c >> 4, g = c & 15;
        int row = row0 + r;
        unsigned byte = r * 256 + (((unsigned)g * 16) ^ (((unsigned)r & 7) << 4));
        short8_t va = {0, 0, 0, 0, 0, 0, 0, 0}, vh = va;
        if (row < n) {
            va = *reinterpret_cast<const short8_t*>(agg + (size_t)row * HIDC + g * 8);
            vh = *reinterpret_cast<const short8_t*>(h + (size_t)row * HIDC + g * 8);
        }
        *reinterpret_cast<short8_t*>(reinterpret_cast<char*>(&sA[0][0]) + byte) = va;
        *reinterpret_cast<short8_t*>(reinterpret_cast<char*>(&sA[1][0]) + byte) = vh;
    }
    __syncthreads();

    f32x4 acc[3];
#pragma unroll
    for (int ci = 0; ci < 3; ci++) acc[ci] = (f32x4){0.f, 0.f, 0.f, 0.f};

#pragma unroll
    for (int ks = 0; ks < 4; ks++) {
        short8_t af[2];
        int r = w * 16 + cc;
        unsigned byte = r * 256 + (((unsigned)(ks * 64 + kg * 16)) ^ (((unsigned)r & 7) << 4));
#pragma unroll
        for (int s = 0; s < 2; s++)
            af[s] = *reinterpret_cast<const short8_t*>(reinterpret_cast<const char*>(&sA[s][0]) + byte);
#pragma unroll
        for (int s = 0; s < 2; s++)
#pragma unroll
            for (int ci = 0; ci < 3; ci++)
                acc[ci] = __builtin_amdgcn_mfma_f32_16x16x32_bf16(af[s], bfrag[s][ci][ks], acc[ci], 0, 0, 0);
    }

#pragma unroll
    for (int reg = 0; reg < 4; reg++) {
        int row = row0 + w * 16 + kg * 4 + reg;
        float val[3];
        float m = -INFINITY;
#pragma unroll
        for (int ci = 0; ci < 3; ci++) {
            int col = ci * 16 + cc;
            val[ci] = (col < OUTC) ? (acc[ci][reg] + bl[col]) : -INFINITY;
            m = fmaxf(m, val[ci]);
        }
#pragma unroll
        for (int off = 1; off < 16; off <<= 1) m = fmaxf(m, __shfl_xor(m, off));
        float s = 0.f;
#pragma unroll
        for (int ci = 0; ci < 3; ci++) {
            int col = ci * 16 + cc;
            if (col < OUTC) s += __expf(val[ci] - m);
        }
#pragma unroll
        for (int off = 1; off < 16; off <<= 1) s += __shfl_xor(s, off);
        float lse = m + logf(s);
        if (row < n) {
#pragma unroll
            for (int ci = 0; ci < 3; ci++) {
                int col = ci * 16 + cc;
                if (col < OUTC) out[(size_t)row * OUTC + col] = val[ci] - lse;
            }
        }
    }
}

// ---------------- Launch ----------------

extern "C" void kernel_launch(void* const* d_in, const int* in_sizes, int n_in,
                              void* d_out, int out_size, void* d_ws, size_t ws_size,
                              hipStream_t stream) {
    const float* x        = (const float*)d_in[0];
    const int*   ei       = (const int*)d_in[1];
    const float* inproj_w = (const float*)d_in[2];
    const float* inproj_b = (const float*)d_in[3];
    const float* wl_h     = (const float*)d_in[4];
    const float* bl_h     = (const float*)d_in[5];
    const float* wr_h     = (const float*)d_in[6];
    const float* wl_out   = (const float*)d_in[7];
    const float* bl_out   = (const float*)d_in[8];
    const float* wr_out   = (const float*)d_in[9];
    float* out = (float*)d_out;

    int n  = in_sizes[0] / INC;   // 100000
    int ne = in_sizes[1] / 2;     // 1600000
    const int* src = ei;
    const int* dst = ei + ne;

    char* ws = (char*)d_ws;
    size_t off = 0;
    auto alloc = [&](size_t bytes) -> void* {
        void* p = ws + off;
        off = (off + bytes + 255) & ~(size_t)255;
        return p;
    };
    float*          inp    = (float*)alloc((size_t)n * HIDC * 4);
    unsigned short* h      = (unsigned short*)alloc((size_t)n * HIDC * 2);
    unsigned short* agg    = (unsigned short*)alloc((size_t)n * HIDC * 2);
    unsigned short* wt     = (unsigned short*)alloc((size_t)6 * 16384 * 2);
    unsigned short* wt2    = (unsigned short*)alloc((size_t)2 * 48 * 128 * 2);
    int*   deg    = (int*)alloc((size_t)n * 4);
    float* invdeg = (float*)alloc((size_t)n * 4);
    int*   local_s= (int*)alloc((size_t)n * 4);
    int*   bsum   = (int*)alloc(512 * 4);
    int*   offs   = (int*)alloc((size_t)(n + 1) * 4);
    int*   curs   = (int*)alloc((size_t)n * 4);
    int*   csr    = (int*)alloc((size_t)ne * 4);

    hipMemsetAsync(deg, 0, (size_t)n * 4, stream);
    hipMemsetAsync(curs, 0, (size_t)n * 4, stream);

    int nbE = (ne + 255) / 256;
    int nbN = (n + 255) / 256;
    k_deg<<<nbE, 256, 0, stream>>>(dst, deg, ne);
    k_scan1<<<nbN, 256, 0, stream>>>(deg, local_s, bsum, n);
    k_scan2<<<1, 512, 0, stream>>>(bsum, nbN);
    k_scan3<<<nbN, 256, 0, stream>>>(local_s, bsum, offs, n, ne);
    k_invdeg<<<nbN, 256, 0, stream>>>(deg, invdeg, n);

    // partitioned fill: 256 edge chunks x 8 dst-partitions (p = blockIdx & 7 -> XCD)
    int psize = (n + 7) / 8;                 // 12500 nodes per partition
    int nchunk = 256;
    int ch = (ne + nchunk - 1) / nchunk;     // 6250 edges per chunk
    k_fill<<<nchunk * 8, 256, 0, stream>>>(src, dst, offs, curs, csr, ne, psize, ch);

    k_prepw<<<(6 * 16384 + 255) / 256, 256, 0, stream>>>(wl_h, wr_h, wt);
    k_prepw_out<<<(2 * 48 * 128 + 255) / 256, 256, 0, stream>>>(wl_out, wr_out, wt2);

    int nbR = (n + 15) / 16;
    int nbA = (n + 3) / 4;
    int nbT = (n + 31) / 32;
    int nbO = (n + 63) / 64;
    k_inproj<<<nbR, 256, 0, stream>>>(x, inproj_w, inproj_b, inp, h, n);
    for (int l = 0; l < 3; ++l) {
        k_agg<<<nbA, 256, 0, stream>>>(h, csr, offs, invdeg, agg, n);
        k_sage_mfma<<<nbT, 256, 0, stream>>>(agg, h, inp, wt + (size_t)l * 2 * 16384,
                                             bl_h + (size_t)l * HIDC, n);
    }
    k_agg<<<nbA, 256, 0, stream>>>(h, csr, offs, invdeg, agg, n);
    k_out_mfma<<<nbO, 256, 0, stream>>>(agg, h, wt2, bl_out, out, n);
}

// Round 7
// 592.333 us; speedup vs baseline: 3.3641x; 1.0665x over previous
//
#include <hip/hip_runtime.h>
#include <math.h>

#define HIDC 128
#define INC 100
#define OUTC 47

typedef __attribute__((ext_vector_type(8))) short short8_t;   // 8 bf16 (4 VGPRs)
typedef __attribute__((ext_vector_type(4))) float f32x4;      // MFMA accumulator

__device__ inline unsigned short f2bf(float f) {
    unsigned u = __builtin_bit_cast(unsigned, f);
    unsigned r = (u + 0x7FFFu + ((u >> 16) & 1u)) >> 16;      // RNE
    return (unsigned short)r;
}
__device__ inline float bf2f(unsigned short s) {
    unsigned u = ((unsigned)s) << 16;
    return __builtin_bit_cast(float, u);
}

// ---------------- CSR build ----------------

__global__ __launch_bounds__(256) void k_deg(const int* __restrict__ dst, int* __restrict__ deg, int ne) {
    int e = blockIdx.x * 256 + threadIdx.x;
    if (e < ne) atomicAdd(&deg[dst[e]], 1);
}

__global__ __launch_bounds__(256) void k_scan1(const int* __restrict__ deg, int* __restrict__ local_s,
                                               int* __restrict__ bsum, int n) {
    __shared__ int s[256];
    int t = threadIdx.x;
    int i = blockIdx.x * 256 + t;
    int v = (i < n) ? deg[i] : 0;
    s[t] = v;
    __syncthreads();
    for (int off = 1; off < 256; off <<= 1) {
        int add = (t >= off) ? s[t - off] : 0;
        __syncthreads();
        s[t] += add;
        __syncthreads();
    }
    if (i < n) local_s[i] = s[t] - v;
    if (t == 255) bsum[blockIdx.x] = s[255];
}

__global__ __launch_bounds__(512) void k_scan2(int* __restrict__ bsum, int nb) {
    __shared__ int s[512];
    int t = threadIdx.x;
    int v = (t < nb) ? bsum[t] : 0;
    s[t] = v;
    __syncthreads();
    for (int off = 1; off < 512; off <<= 1) {
        int add = (t >= off) ? s[t - off] : 0;
        __syncthreads();
        s[t] += add;
        __syncthreads();
    }
    if (t < nb) bsum[t] = s[t] - v;
}

__global__ __launch_bounds__(256) void k_scan3(const int* __restrict__ local_s, const int* __restrict__ bsum,
                                               int* __restrict__ offs, int n, int ne) {
    int i = blockIdx.x * 256 + threadIdx.x;
    if (i < n) offs[i] = local_s[i] + bsum[blockIdx.x];
    if (i == 0) offs[n] = ne;
}

__global__ __launch_bounds__(256) void k_invdeg(const int* __restrict__ deg, float* __restrict__ invdeg, int n) {
    int i = blockIdx.x * 256 + threadIdx.x;
    if (i < n) invdeg[i] = 1.0f / (float)max(deg[i], 1);
}

// Partitioned fill: block handles partition p = blockIdx.x & 7 (XCD round-robin)
// over edge chunk blockIdx.x >> 3; writes stay in one XCD's L2 slice.

__global__ __launch_bounds__(256) void k_fill(const int* __restrict__ src, const int* __restrict__ dst,
                                              const int* __restrict__ offs, int* __restrict__ curs,
                                              int* __restrict__ csr, int ne, int psize, int ch) {
    int p = blockIdx.x & 7;
    int chunk = blockIdx.x >> 3;
    int lo = p * psize;
    int e0 = chunk * ch;
    int e1 = min(ne, e0 + ch);
    for (int e = e0 + threadIdx.x; e < e1; e += 256) {
        int d = dst[e];
        if ((unsigned)(d - lo) < (unsigned)psize) {
            int pos = atomicAdd(&curs[d], 1);
            csr[offs[d] + pos] = src[e];
        }
    }
}

// ---------------- Weight prep ----------------

// hidden wt[(l*2+s)][n][k] bf16
__global__ __launch_bounds__(256) void k_prepw(const float* __restrict__ wl_h, const float* __restrict__ wr_h,
                                               unsigned short* __restrict__ wt) {
    int idx = blockIdx.x * 256 + threadIdx.x;
    if (idx >= 6 * 16384) return;
    int m = idx >> 14, rem = idx & 16383;
    int l = m >> 1, s = m & 1;
    const float* srcm = (s == 0 ? wl_h : wr_h) + (size_t)l * 16384;
    wt[idx] = f2bf(srcm[(rem & 127) * 128 + (rem >> 7)]);
}

// out weights: wt2[s][nc][k], nc in [0,48) padded (col 47 = 0)
__global__ __launch_bounds__(256) void k_prepw_out(const float* __restrict__ wl_out,
                                                   const float* __restrict__ wr_out,
                                                   unsigned short* __restrict__ wt2) {
    int idx = blockIdx.x * 256 + threadIdx.x;
    if (idx >= 2 * 48 * 128) return;
    int s = idx / (48 * 128), rem = idx % (48 * 128);
    int nc = rem >> 7, k = rem & 127;
    const float* srcm = (s == 0) ? wl_out : wr_out;
    wt2[idx] = (nc < OUTC) ? f2bf(srcm[k * OUTC + nc]) : 0;
}

// in-proj weights: wtin[nc][k] bf16, K padded 100->128 with zeros
__global__ __launch_bounds__(256) void k_prepw_in(const float* __restrict__ w,
                                                  unsigned short* __restrict__ wtin) {
    int idx = blockIdx.x * 256 + threadIdx.x;
    if (idx >= 128 * 128) return;
    int nc = idx >> 7, k = idx & 127;
    wtin[idx] = (k < INC) ? f2bf(w[k * HIDC + nc]) : 0;
}

// ---------------- Aggregation (pull, mean): wave per node, bf16 rows, 8 edges/iter ----------------

__global__ __launch_bounds__(256) void k_agg(const unsigned short* __restrict__ h, const int* __restrict__ csr,
                                             const int* __restrict__ offs, const float* __restrict__ invdeg,
                                             unsigned short* __restrict__ agg, int n) {
    int wv = threadIdx.x >> 6, lane = threadIdx.x & 63;
    int v = blockIdx.x * 4 + wv;
    if (v >= n) return;
    int q = lane >> 4, c = lane & 15;   // q: edge slot, c: 16B chunk (8 bf16)
    int e0 = offs[v], e1 = offs[v + 1];
    float acc[8] = {0, 0, 0, 0, 0, 0, 0, 0};
    for (int e = e0 + q; e < e1; e += 8) {
        int s0 = csr[e];
        bool has2 = (e + 4) < e1;
        int s1 = has2 ? csr[e + 4] : s0;
        short8_t t0 = *reinterpret_cast<const short8_t*>(h + (size_t)s0 * HIDC + c * 8);
        short8_t t1 = *reinterpret_cast<const short8_t*>(h + (size_t)s1 * HIDC + c * 8);
#pragma unroll
        for (int i = 0; i < 8; i++) {
            acc[i] += bf2f((unsigned short)t0[i]);
            if (has2) acc[i] += bf2f((unsigned short)t1[i]);
        }
    }
#pragma unroll
    for (int i = 0; i < 8; i++) {
        acc[i] += __shfl_xor(acc[i], 16);
        acc[i] += __shfl_xor(acc[i], 32);
    }
    if (q == 0) {
        float s = invdeg[v];
        unsigned short o[8];
#pragma unroll
        for (int i = 0; i < 8; i++) o[i] = f2bf(acc[i] * s);
        *reinterpret_cast<short8_t*>(agg + (size_t)v * HIDC + c * 8) = *reinterpret_cast<const short8_t*>(o);
    }
}

// ---------------- Input projection via MFMA: inp = x@W + b (bf16); h = relu(inp) (bf16) ----------------
// 32-row tile, 4 waves; wave w owns cols [32w,32w+32). x staged fp32->bf16 into swizzled LDS,
// K padded 100->128 (zeros on both operands). Same A/B k-map as k_sage_mfma => exact.

__global__ __launch_bounds__(256) void k_inproj_mfma(const float* __restrict__ x,
                                                     const unsigned short* __restrict__ wtin, // [128][128]
                                                     const float* __restrict__ b,
                                                     unsigned short* __restrict__ inp,
                                                     unsigned short* __restrict__ h, int n) {
    __shared__ unsigned short sX[32 * 128];
    int t = threadIdx.x;
    int w = t >> 6, lane = t & 63;
    int cc = lane & 15, kg = lane >> 4;
    int row0 = blockIdx.x * 32;

    short8_t bfrag[2][4];
#pragma unroll
    for (int ci = 0; ci < 2; ci++) {
        int ncol = 32 * w + ci * 16 + cc;
        const unsigned short* bp = wtin + ncol * 128 + kg * 8;
#pragma unroll
        for (int ks = 0; ks < 4; ks++)
            bfrag[ci][ks] = *reinterpret_cast<const short8_t*>(bp + ks * 32);
    }

    // stage: thread handles row r, 16-col segment seg (float4-aligned: row stride 400B, seg 64B)
    {
        int r = t >> 3, seg = t & 7;
        int row = row0 + r;
        float v[16];
#pragma unroll
        for (int i = 0; i < 16; i++) v[i] = 0.f;
        if (row < n) {
            const float* xr = x + (size_t)row * INC;
            if (seg < 6) {
#pragma unroll
                for (int j = 0; j < 4; j++) {
                    float4 f = *reinterpret_cast<const float4*>(xr + seg * 16 + j * 4);
                    v[j * 4 + 0] = f.x; v[j * 4 + 1] = f.y; v[j * 4 + 2] = f.z; v[j * 4 + 3] = f.w;
                }
            } else if (seg == 6) {
                float4 f = *reinterpret_cast<const float4*>(xr + 96);   // cols 96..99; 100..111 stay 0
                v[0] = f.x; v[1] = f.y; v[2] = f.z; v[3] = f.w;
            }
        }
        unsigned short o[16];
#pragma unroll
        for (int i = 0; i < 16; i++) o[i] = f2bf(v[i]);
#pragma unroll
        for (int half = 0; half < 2; half++) {
            int g = seg * 2 + half;
            unsigned byte = r * 256 + (((unsigned)g * 16) ^ (((unsigned)r & 7) << 4));
            *reinterpret_cast<short8_t*>(reinterpret_cast<char*>(sX) + byte) =
                *reinterpret_cast<const short8_t*>(&o[half * 8]);
        }
    }
    __syncthreads();

    f32x4 acc[2][2];
#pragma unroll
    for (int rt = 0; rt < 2; rt++)
#pragma unroll
        for (int ci = 0; ci < 2; ci++) acc[rt][ci] = (f32x4){0.f, 0.f, 0.f, 0.f};

#pragma unroll
    for (int ks = 0; ks < 4; ks++) {
        short8_t af[2];
#pragma unroll
        for (int rt = 0; rt < 2; rt++) {
            int r = rt * 16 + cc;
            unsigned byte = r * 256 + (((unsigned)(ks * 64 + kg * 16)) ^ (((unsigned)r & 7) << 4));
            af[rt] = *reinterpret_cast<const short8_t*>(reinterpret_cast<const char*>(sX) + byte);
        }
#pragma unroll
        for (int rt = 0; rt < 2; rt++)
#pragma unroll
            for (int ci = 0; ci < 2; ci++)
                acc[rt][ci] = __builtin_amdgcn_mfma_f32_16x16x32_bf16(af[rt], bfrag[ci][ks],
                                                                      acc[rt][ci], 0, 0, 0);
    }

#pragma unroll
    for (int rt = 0; rt < 2; rt++)
#pragma unroll
        for (int ci = 0; ci < 2; ci++) {
            int col = 32 * w + ci * 16 + cc;
            float bv = b[col];
#pragma unroll
            for (int reg = 0; reg < 4; reg++) {
                int row = row0 + rt * 16 + kg * 4 + reg;
                if (row < n) {
                    float v = acc[rt][ci][reg] + bv;
                    inp[(size_t)row * HIDC + col] = f2bf(v);
                    h[(size_t)row * HIDC + col] = f2bf(fmaxf(v, 0.f));
                }
            }
        }
}

// ---------------- Hidden SAGE layer via MFMA (inp now bf16) ----------------

__global__ __launch_bounds__(256) void k_sage_mfma(const unsigned short* __restrict__ agg,
                                                   unsigned short* __restrict__ h,
                                                   const unsigned short* __restrict__ inp,
                                                   const unsigned short* __restrict__ wt,  // [2][128][128]
                                                   const float* __restrict__ bl, int n) {
    __shared__ unsigned short sA[2][32 * 128];
    int t = threadIdx.x;
    int w = t >> 6, lane = t & 63;
    int cc = lane & 15, kg = lane >> 4;
    int row0 = blockIdx.x * 32;

    short8_t bfrag[2][2][4];
#pragma unroll
    for (int s = 0; s < 2; s++)
#pragma unroll
        for (int ci = 0; ci < 2; ci++) {
            int ncol = 32 * w + ci * 16 + cc;
            const unsigned short* bp = wt + s * 16384 + ncol * 128 + kg * 8;
#pragma unroll
            for (int ks = 0; ks < 4; ks++)
                bfrag[s][ci][ks] = *reinterpret_cast<const short8_t*>(bp + ks * 32);
        }

    for (int c = t; c < 512; c += 256) {
        int r = c >> 4, g = c & 15;
        int row = row0 + r;
        unsigned byte = r * 256 + (((unsigned)g * 16) ^ (((unsigned)r & 7) << 4));
        short8_t va = {0, 0, 0, 0, 0, 0, 0, 0}, vh = va;
        if (row < n) {
            va = *reinterpret_cast<const short8_t*>(agg + (size_t)row * HIDC + g * 8);
            vh = *reinterpret_cast<const short8_t*>(h + (size_t)row * HIDC + g * 8);
        }
        *reinterpret_cast<short8_t*>(reinterpret_cast<char*>(&sA[0][0]) + byte) = va;
        *reinterpret_cast<short8_t*>(reinterpret_cast<char*>(&sA[1][0]) + byte) = vh;
    }
    __syncthreads();

    f32x4 acc[2][2];
#pragma unroll
    for (int rt = 0; rt < 2; rt++)
#pragma unroll
        for (int ci = 0; ci < 2; ci++) acc[rt][ci] = (f32x4){0.f, 0.f, 0.f, 0.f};

#pragma unroll
    for (int ks = 0; ks < 4; ks++) {
        short8_t af[2][2];
#pragma unroll
        for (int s = 0; s < 2; s++)
#pragma unroll
            for (int rt = 0; rt < 2; rt++) {
                int r = rt * 16 + cc;
                unsigned byte = r * 256 + (((unsigned)(ks * 64 + kg * 16)) ^ (((unsigned)r & 7) << 4));
                af[s][rt] = *reinterpret_cast<const short8_t*>(reinterpret_cast<const char*>(&sA[s][0]) + byte);
            }
#pragma unroll
        for (int s = 0; s < 2; s++)
#pragma unroll
            for (int rt = 0; rt < 2; rt++)
#pragma unroll
                for (int ci = 0; ci < 2; ci++)
                    acc[rt][ci] = __builtin_amdgcn_mfma_f32_16x16x32_bf16(af[s][rt], bfrag[s][ci][ks],
                                                                          acc[rt][ci], 0, 0, 0);
    }

#pragma unroll
    for (int rt = 0; rt < 2; rt++)
#pragma unroll
        for (int ci = 0; ci < 2; ci++) {
            int col = 32 * w + ci * 16 + cc;
            float bv = bl[col];
#pragma unroll
            for (int reg = 0; reg < 4; reg++) {
                int row = row0 + rt * 16 + kg * 4 + reg;
                if (row < n) {
                    float v = acc[rt][ci][reg] + bv;
                    v = fmaxf(v, 0.f) + 0.2f * bf2f(inp[(size_t)row * HIDC + col]);
                    h[(size_t)row * HIDC + col] = f2bf(v);
                }
            }
        }
}

// ---------------- Output layer via MFMA + in-register log_softmax ----------------

__global__ __launch_bounds__(256) void k_out_mfma(const unsigned short* __restrict__ agg,
                                                  const unsigned short* __restrict__ h,
                                                  const unsigned short* __restrict__ wt2,  // [2][48][128]
                                                  const float* __restrict__ bl,
                                                  float* __restrict__ out, int n) {
    __shared__ unsigned short sA[2][64 * 128];
    int t = threadIdx.x;
    int w = t >> 6, lane = t & 63;
    int cc = lane & 15, kg = lane >> 4;
    int row0 = blockIdx.x * 64;

    short8_t bfrag[2][3][4];
#pragma unroll
    for (int s = 0; s < 2; s++)
#pragma unroll
        for (int ci = 0; ci < 3; ci++) {
            const unsigned short* bp = wt2 + s * (48 * 128) + (ci * 16 + cc) * 128 + kg * 8;
#pragma unroll
            for (int ks = 0; ks < 4; ks++)
                bfrag[s][ci][ks] = *reinterpret_cast<const short8_t*>(bp + ks * 32);
        }

    for (int c = t; c < 1024; c += 256) {
        int r = c >> 4, g = c & 15;
        int row = row0 + r;
        unsigned byte = r * 256 + (((unsigned)g * 16) ^ (((unsigned)r & 7) << 4));
        short8_t va = {0, 0, 0, 0, 0, 0, 0, 0}, vh = va;
        if (row < n) {
            va = *reinterpret_cast<const short8_t*>(agg + (size_t)row * HIDC + g * 8);
            vh = *reinterpret_cast<const short8_t*>(h + (size_t)row * HIDC + g * 8);
        }
        *reinterpret_cast<short8_t*>(reinterpret_cast<char*>(&sA[0][0]) + byte) = va;
        *reinterpret_cast<short8_t*>(reinterpret_cast<char*>(&sA[1][0]) + byte) = vh;
    }
    __syncthreads();

    f32x4 acc[3];
#pragma unroll
    for (int ci = 0; ci < 3; ci++) acc[ci] = (f32x4){0.f, 0.f, 0.f, 0.f};

#pragma unroll
    for (int ks = 0; ks < 4; ks++) {
        short8_t af[2];
        int r = w * 16 + cc;
        unsigned byte = r * 256 + (((unsigned)(ks * 64 + kg * 16)) ^ (((unsigned)r & 7) << 4));
#pragma unroll
        for (int s = 0; s < 2; s++)
            af[s] = *reinterpret_cast<const short8_t*>(reinterpret_cast<const char*>(&sA[s][0]) + byte);
#pragma unroll
        for (int s = 0; s < 2; s++)
#pragma unroll
            for (int ci = 0; ci < 3; ci++)
                acc[ci] = __builtin_amdgcn_mfma_f32_16x16x32_bf16(af[s], bfrag[s][ci][ks], acc[ci], 0, 0, 0);
    }

#pragma unroll
    for (int reg = 0; reg < 4; reg++) {
        int row = row0 + w * 16 + kg * 4 + reg;
        float val[3];
        float m = -INFINITY;
#pragma unroll
        for (int ci = 0; ci < 3; ci++) {
            int col = ci * 16 + cc;
            val[ci] = (col < OUTC) ? (acc[ci][reg] + bl[col]) : -INFINITY;
            m = fmaxf(m, val[ci]);
        }
#pragma unroll
        for (int off = 1; off < 16; off <<= 1) m = fmaxf(m, __shfl_xor(m, off));
        float s = 0.f;
#pragma unroll
        for (int ci = 0; ci < 3; ci++) {
            int col = ci * 16 + cc;
            if (col < OUTC) s += __expf(val[ci] - m);
        }
#pragma unroll
        for (int off = 1; off < 16; off <<= 1) s += __shfl_xor(s, off);
        float lse = m + logf(s);
        if (row < n) {
#pragma unroll
            for (int ci = 0; ci < 3; ci++) {
                int col = ci * 16 + cc;
                if (col < OUTC) out[(size_t)row * OUTC + col] = val[ci] - lse;
            }
        }
    }
}

// ---------------- Launch ----------------

extern "C" void kernel_launch(void* const* d_in, const int* in_sizes, int n_in,
                              void* d_out, int out_size, void* d_ws, size_t ws_size,
                              hipStream_t stream) {
    const float* x        = (const float*)d_in[0];
    const int*   ei       = (const int*)d_in[1];
    const float* inproj_w = (const float*)d_in[2];
    const float* inproj_b = (const float*)d_in[3];
    const float* wl_h     = (const float*)d_in[4];
    const float* bl_h     = (const float*)d_in[5];
    const float* wr_h     = (const float*)d_in[6];
    const float* wl_out   = (const float*)d_in[7];
    const float* bl_out   = (const float*)d_in[8];
    const float* wr_out   = (const float*)d_in[9];
    float* out = (float*)d_out;

    int n  = in_sizes[0] / INC;   // 100000
    int ne = in_sizes[1] / 2;     // 1600000
    const int* src = ei;
    const int* dst = ei + ne;

    char* ws = (char*)d_ws;
    size_t off = 0;
    auto alloc = [&](size_t bytes) -> void* {
        void* p = ws + off;
        off = (off + bytes + 255) & ~(size_t)255;
        return p;
    };
    unsigned short* inp    = (unsigned short*)alloc((size_t)n * HIDC * 2);
    unsigned short* h      = (unsigned short*)alloc((size_t)n * HIDC * 2);
    unsigned short* agg    = (unsigned short*)alloc((size_t)n * HIDC * 2);
    unsigned short* wt     = (unsigned short*)alloc((size_t)6 * 16384 * 2);
    unsigned short* wt2    = (unsigned short*)alloc((size_t)2 * 48 * 128 * 2);
    unsigned short* wtin   = (unsigned short*)alloc((size_t)128 * 128 * 2);
    int*   deg    = (int*)alloc((size_t)n * 4);
    float* invdeg = (float*)alloc((size_t)n * 4);
    int*   local_s= (int*)alloc((size_t)n * 4);
    int*   bsum   = (int*)alloc(512 * 4);
    int*   offs   = (int*)alloc((size_t)(n + 1) * 4);
    int*   curs   = (int*)alloc((size_t)n * 4);
    int*   csr    = (int*)alloc((size_t)ne * 4);

    hipMemsetAsync(deg, 0, (size_t)n * 4, stream);
    hipMemsetAsync(curs, 0, (size_t)n * 4, stream);

    int nbE = (ne + 255) / 256;
    int nbN = (n + 255) / 256;
    k_deg<<<nbE, 256, 0, stream>>>(dst, deg, ne);
    k_scan1<<<nbN, 256, 0, stream>>>(deg, local_s, bsum, n);
    k_scan2<<<1, 512, 0, stream>>>(bsum, nbN);
    k_scan3<<<nbN, 256, 0, stream>>>(local_s, bsum, offs, n, ne);
    k_invdeg<<<nbN, 256, 0, stream>>>(deg, invdeg, n);

    int psize = (n + 7) / 8;
    int nchunk = 256;
    int ch = (ne + nchunk - 1) / nchunk;
    k_fill<<<nchunk * 8, 256, 0, stream>>>(src, dst, offs, curs, csr, ne, psize, ch);

    k_prepw<<<(6 * 16384 + 255) / 256, 256, 0, stream>>>(wl_h, wr_h, wt);
    k_prepw_out<<<(2 * 48 * 128 + 255) / 256, 256, 0, stream>>>(wl_out, wr_out, wt2);
    k_prepw_in<<<(128 * 128 + 255) / 256, 256, 0, stream>>>(inproj_w, wtin);

    int nbA = (n + 3) / 4;
    int nbT = (n + 31) / 32;
    int nbO = (n + 63) / 64;
    k_inproj_mfma<<<nbT, 256, 0, stream>>>(x, wtin, inproj_b, inp, h, n);
    for (int l = 0; l < 3; ++l) {
        k_agg<<<nbA, 256, 0, stream>>>(h, csr, offs, invdeg, agg, n);
        k_sage_mfma<<<nbT, 256, 0, stream>>>(agg, h, inp, wt + (size_t)l * 2 * 16384,
                                             bl_h + (size_t)l * HIDC, n);
    }
    k_agg<<<nbA, 256, 0, stream>>>(h, csr, offs, invdeg, agg, n);
    k_out_mfma<<<nbO, 256, 0, stream>>>(agg, h, wt2, bl_out, out, n);
}